// Round 3
// baseline (360.153 us; speedup 1.0000x reference)
//
#include <hip/hip_runtime.h>
#include <stdint.h>

#define BATCH 32
#define SEQ   1024
#define DIM   64
#define NKT   (SEQ / 64)

typedef uint16_t u16;
typedef uint32_t u32;
typedef unsigned long long u64;
typedef __attribute__((ext_vector_type(8))) __bf16 bf16x8;
typedef __attribute__((ext_vector_type(4))) float  f32x4;
typedef __attribute__((ext_vector_type(4))) u32    u32x4;

__device__ __forceinline__ float fexp2(float x) {
#if __has_builtin(__builtin_amdgcn_exp2f)
    return __builtin_amdgcn_exp2f(x);
#else
    return exp2f(x);
#endif
}

__device__ __forceinline__ u16 f2bf(float f) {
    u32 x = __builtin_bit_cast(u32, f);
    x += 0x7FFFu + ((x >> 16) & 1u);   // round-to-nearest-even
    return (u16)(x >> 16);
}

// 8 contiguous f32 -> bf16x8 fragment (RNE)
__device__ __forceinline__ bf16x8 cvt8(const float* __restrict__ p) {
    f32x4 a = *reinterpret_cast<const f32x4*>(p);
    f32x4 b = *reinterpret_cast<const f32x4*>(p + 4);
    u16 t[8];
    t[0] = f2bf(a[0]); t[1] = f2bf(a[1]); t[2] = f2bf(a[2]); t[3] = f2bf(a[3]);
    t[4] = f2bf(b[0]); t[5] = f2bf(b[1]); t[6] = f2bf(b[2]); t[7] = f2bf(b[3]);
    return __builtin_bit_cast(bf16x8, *reinterpret_cast<u32x4*>(t));
}

// scaled variant (scale folded into the bf16 fragment)
__device__ __forceinline__ bf16x8 cvt8s(const float* __restrict__ p, float s) {
    f32x4 a = *reinterpret_cast<const f32x4*>(p);
    f32x4 b = *reinterpret_cast<const f32x4*>(p + 4);
    u16 t[8];
    t[0] = f2bf(a[0] * s); t[1] = f2bf(a[1] * s); t[2] = f2bf(a[2] * s); t[3] = f2bf(a[3] * s);
    t[4] = f2bf(b[0] * s); t[5] = f2bf(b[1] * s); t[6] = f2bf(b[2] * s); t[7] = f2bf(b[3] * s);
    return __builtin_bit_cast(bf16x8, *reinterpret_cast<u32x4*>(t));
}

__device__ __forceinline__ bf16x8 ldg8(const u16* p) {
    u32x4 u = *reinterpret_cast<const u32x4*>(p);
    return __builtin_bit_cast(bf16x8, u);
}

// ---------------------------------------------------------------------------
// Fused prepass:
//  - ALL 8192 blocks: mask int32 [B][S][S] -> ballot-native bitwords.
//    Layout: bits[row*16 + g*4 + i], g = 256-col group, i = col%4.
//    Word i bit l = mask[row][g*256 + 4l + i].
//    One wave = one row; all 4 group-loads issued upfront (4-deep MLP).
//  - blocks < 512 additionally: V f32 -> Vt bf16 [B][D][S] (LDS transpose)
//    and K f32 -> bf16 row-major.
// ---------------------------------------------------------------------------
__global__ __launch_bounds__(256) void prep_kernel(
    const float* __restrict__ kg, const float* __restrict__ vg,
    const int* __restrict__ mask, u16* __restrict__ kb,
    u16* __restrict__ vtb_, u64* __restrict__ bits) {
    __shared__ u16 tile[64][72];
    const int t    = threadIdx.x;
    const int wave = t >> 6;
    const int lane = t & 63;
    const int row  = blockIdx.x * 4 + wave;   // 0..32767 = b*SEQ + seq_row

    // ---- mask packing: 4 groups (one row), all loads in flight upfront ----
    const int* mrow = mask + (size_t)row * SEQ + lane * 4;
    u32x4 x0 = *reinterpret_cast<const u32x4*>(mrow);
    u32x4 x1 = *reinterpret_cast<const u32x4*>(mrow + 256);
    u32x4 x2 = *reinterpret_cast<const u32x4*>(mrow + 512);
    u32x4 x3 = *reinterpret_cast<const u32x4*>(mrow + 768);

#define MPROC(x, g)                                                           \
    {                                                                         \
        int nib = (x[0] != 0) | ((x[1] != 0) << 1) |                          \
                  ((x[2] != 0) << 2) | ((x[3] != 0) << 3);                    \
        u64 b0 = __ballot(nib & 1);                                           \
        u64 b1 = __ballot(nib & 2);                                           \
        u64 b2 = __ballot(nib & 4);                                           \
        u64 b3 = __ballot(nib & 8);                                           \
        if (lane < 4) {                                                       \
            u64 w = (lane == 0) ? b0 : (lane == 1) ? b1 : (lane == 2) ? b2 : b3; \
            bits[(size_t)row * 16 + (g) * 4 + lane] = w;                      \
        }                                                                     \
    }
    MPROC(x0, 0)
    MPROC(x1, 1)
    MPROC(x2, 2)
    MPROC(x3, 3)
#undef MPROC

    // ---- V transpose + K bf16 for the first 512 blocks --------------------
    if (blockIdx.x < 512) {
        const int b  = blockIdx.x >> 4;
        const int k0 = (blockIdx.x & 15) * 64;

        // K f32 -> bf16 row-major (64x64 tile)
        {
            int kk = t >> 2;
            int d0 = (t & 3) * 16;
            const float* src = kg + ((size_t)b * SEQ + k0 + kk) * DIM + d0;
            u16 tmp[16];
#pragma unroll
            for (int i = 0; i < 4; ++i) {
                f32x4 a = *reinterpret_cast<const f32x4*>(src + i * 4);
                tmp[i * 4 + 0] = f2bf(a[0]); tmp[i * 4 + 1] = f2bf(a[1]);
                tmp[i * 4 + 2] = f2bf(a[2]); tmp[i * 4 + 3] = f2bf(a[3]);
            }
            u16* dst = kb + ((size_t)b * SEQ + k0 + kk) * DIM + d0;
            *reinterpret_cast<u32x4*>(dst)     = *reinterpret_cast<u32x4*>(tmp);
            *reinterpret_cast<u32x4*>(dst + 8) = *reinterpret_cast<u32x4*>(tmp + 8);
        }

        // V transpose via LDS
        const float* vb  = vg  + (size_t)b * SEQ * DIM;
        u16*         vtb = vtb_ + (size_t)b * DIM * SEQ;
        {
            int kk = t >> 2;
            int d0 = (t & 3) * 16;
            const float* src = vb + (size_t)(k0 + kk) * DIM + d0;
            u16 tmp[16];
#pragma unroll
            for (int i = 0; i < 4; ++i) {
                f32x4 a = *reinterpret_cast<const f32x4*>(src + i * 4);
                tmp[i * 4 + 0] = f2bf(a[0]); tmp[i * 4 + 1] = f2bf(a[1]);
                tmp[i * 4 + 2] = f2bf(a[2]); tmp[i * 4 + 3] = f2bf(a[3]);
            }
            *reinterpret_cast<u32x4*>(&tile[kk][d0])     = *reinterpret_cast<u32x4*>(tmp);
            *reinterpret_cast<u32x4*>(&tile[kk][d0 + 8]) = *reinterpret_cast<u32x4*>(tmp + 8);
        }
        __syncthreads();
#pragma unroll
        for (int i = 0; i < 2; ++i) {
            int d  = t / 8 + i * 32;
            int ks = (t % 8) * 8;
            u16 tmp[8];
#pragma unroll
            for (int j = 0; j < 8; ++j) tmp[j] = tile[ks + j][d];
            *reinterpret_cast<u32x4*>(vtb + (size_t)d * SEQ + k0 + ks) =
                *reinterpret_cast<u32x4*>(tmp);
        }
    }
}

// ---------------------------------------------------------------------------
// Fused rel-pos attention, split-K across wave pairs.
// 512 threads = 8 waves: wave (wq = w&3, wk = w>>2).
// New vs round 2:
//  - far-tile shortcut: only kt in {qt-1,qt,qt+1} needs the qp gather; all
//    other tiles use a per-row constant folded into the softmax offset
//    (no per-element add, no LDS gather, no clamp).
//  - cross-iteration K-fragment register prefetch (loads for kt+1 issued
//    under kt's softmax+PV), V first-halves issued before softmax.
// ---------------------------------------------------------------------------
__global__ __launch_bounds__(512, 4) void attn_fast3(
    const float* __restrict__ qg, const u16* __restrict__ kbf,
    const u16* __restrict__ vt, const u64* __restrict__ mbits,
    const float* __restrict__ ptg, float* __restrict__ outg) {
    __shared__ float qp[64][132];        // 33792 B; reused as combine buffer
    __shared__ u16   plds[8][16][72];    // 18432 B, per-wave P tile

    const int b    = blockIdx.y;
    const int q0   = blockIdx.x * 64;
    const int tid  = threadIdx.x;
    const int wave = tid >> 6;
    const int lane = tid & 63;
    const int wq   = wave & 3;
    const int wk   = wave >> 2;
    const int quad = lane >> 4;
    const int c16  = lane & 15;

    const float SC = 0.125f * 1.44269504088896340736f;  // 1/8 * log2(e)

    const float* qb = qg + ((size_t)b * SEQ + q0) * DIM;

    // Q A-fragments, pre-scaled (exp2 space)
    const bf16x8 qA0 = cvt8s(qb + (size_t)(wq * 16 + c16) * DIM + quad * 8, SC);
    const bf16x8 qA1 = cvt8s(qb + (size_t)(wq * 16 + c16) * DIM + 32 + quad * 8, SC);

    // mask bitwords for this wave's rows and its two 4-kt groups (8 loads, L2)
    const size_t rowbase = (size_t)b * SEQ + q0 + wq * 16 + quad * 4;
    u64 w2[2][4];
#pragma unroll
    for (int gg = 0; gg < 2; ++gg)
#pragma unroll
        for (int r = 0; r < 4; ++r)
            w2[gg][r] = mbits[((rowbase + r) * 4 + (wk * 2 + gg)) * 4 + (c16 & 3)];

    // qp[64][129] = (SC*Q)(64x64) . pos_table^T ; jt tiles split across wk
    {
        const int jt0 = wk ? 5 : 0, jt1 = wk ? 9 : 5;
        for (int jt = jt0; jt < jt1; ++jt) {
            int j0 = jt * 16;
            int jr = min(j0 + c16, 128);
            bf16x8 b0 = cvt8(ptg + (size_t)jr * DIM + quad * 8);
            bf16x8 b1 = cvt8(ptg + (size_t)jr * DIM + 32 + quad * 8);
            f32x4 acc = {0.f, 0.f, 0.f, 0.f};
            acc = __builtin_amdgcn_mfma_f32_16x16x32_bf16(qA0, b0, acc, 0, 0, 0);
            acc = __builtin_amdgcn_mfma_f32_16x16x32_bf16(qA1, b1, acc, 0, 0, 0);
            int jcol = j0 + c16;
            if (jcol <= 128) {
#pragma unroll
                for (int r = 0; r < 4; ++r)
                    qp[wq * 16 + quad * 4 + r][jcol] = acc[r];
            }
        }
    }
    __syncthreads();   // qp complete (both halves)

    // per-row saturation constants (left / right), one broadcast LDS read each
    float cL[4], cR[4];
#pragma unroll
    for (int r = 0; r < 4; ++r) {
        cL[r] = qp[wq * 16 + quad * 4 + r][0];
        cR[r] = qp[wq * 16 + quad * 4 + r][128];
    }

    const u16* kb_base  = kbf + (size_t)b * SEQ * DIM;
    const u16* vtb_base = vt  + (size_t)b * DIM * SEQ;
    const int  row_min  = q0 + wq * 16;

    float m_run[4], l_run[4];
    f32x4 O[4];
#pragma unroll
    for (int r = 0; r < 4; ++r) { m_run[r] = -1e30f; l_run[r] = 0.f; }
#pragma unroll
    for (int d = 0; d < 4; ++d) O[d] = f32x4{0.f, 0.f, 0.f, 0.f};

    const int ktbase = wk * 8;

    // prefetch K fragments for first kt
    bf16x8 kc0[4], kc1[4];
#pragma unroll
    for (int sub = 0; sub < 4; ++sub) {
        const u16* kr = kb_base + (size_t)(ktbase * 64 + sub * 16 + c16) * DIM;
        kc0[sub] = ldg8(kr + quad * 8);
        kc1[sub] = ldg8(kr + 32 + quad * 8);
    }

#pragma unroll 1
    for (int j = 0; j < 8; ++j) {
        const int kt   = ktbase + j;
        const int k0   = kt * 64;
        const int j_gg = j >> 2;
        const int j_t  = j & 3;

        // --- S = (SC*Q) . K^T from prefetched fragments --------------------
        f32x4 S[4];
        __builtin_amdgcn_s_setprio(1);
#pragma unroll
        for (int sub = 0; sub < 4; ++sub) {
            f32x4 acc = {0.f, 0.f, 0.f, 0.f};
            acc = __builtin_amdgcn_mfma_f32_16x16x32_bf16(qA0, kc0[sub], acc, 0, 0, 0);
            acc = __builtin_amdgcn_mfma_f32_16x16x32_bf16(qA1, kc1[sub], acc, 0, 0, 0);
            S[sub] = acc;
        }
        __builtin_amdgcn_s_setprio(0);

        // --- prefetch next kt's K fragments (hidden under softmax+PV) ------
        if (j < 7) {
            const int k0n = k0 + 64;
#pragma unroll
            for (int sub = 0; sub < 4; ++sub) {
                const u16* kr = kb_base + (size_t)(k0n + sub * 16 + c16) * DIM;
                kc0[sub] = ldg8(kr + quad * 8);
                kc1[sub] = ldg8(kr + 32 + quad * 8);
            }
        }

        // --- issue current V first-halves early ----------------------------
        bf16x8 vf0[4];
#pragma unroll
        for (int d = 0; d < 4; ++d)
            vf0[d] = ldg8(vtb_base + (size_t)(d * 16 + c16) * SEQ + k0 + quad * 8);

        // --- logits + row-max; far tiles skip gather entirely --------------
        const bool farL = (k0 + 127 <= row_min);
        const bool farR = (k0 >= row_min + 79);
        float m_new[4], ofs[4];
        bool need = false;

        if (farL | farR) {
            // positional term is per-row constant c; fold into offset.
#pragma unroll
            for (int r = 0; r < 4; ++r) {
                const u64 wr = w2[j_gg][r] >> (j_t * 16 + (c16 >> 2));
#pragma unroll
                for (int sub = 0; sub < 4; ++sub) {
                    u32 bit = (u32)(wr >> (sub * 4)) & 1u;
                    S[sub][r] = bit ? -1e30f : S[sub][r];
                }
            }
#pragma unroll
            for (int r = 0; r < 4; ++r) {
                float c = farL ? cL[r] : cR[r];
                float rmax = fmaxf(fmaxf(S[0][r], S[1][r]), fmaxf(S[2][r], S[3][r]));
                rmax = fmaxf(rmax, __shfl_xor(rmax, 1));
                rmax = fmaxf(rmax, __shfl_xor(rmax, 2));
                rmax = fmaxf(rmax, __shfl_xor(rmax, 4));
                rmax = fmaxf(rmax, __shfl_xor(rmax, 8));
                m_new[r] = fmaxf(m_run[r], rmax + c);
                ofs[r]   = m_new[r] - c;          // e = exp2(S - (m_new - c))
                need |= (m_new[r] > m_run[r]);
            }
        } else {
            // near-diagonal tile: per-element qp gather (3 of 16 tiles)
#pragma unroll
            for (int r = 0; r < 4; ++r) {
                const int row_l = quad * 4 + r;
                const int row_g = row_min + row_l;
                const u64 wr = w2[j_gg][r] >> (j_t * 16 + (c16 >> 2));
#pragma unroll
                for (int sub = 0; sub < 4; ++sub) {
                    int col_g = k0 + sub * 16 + c16;
                    int rel = col_g - row_g;
                    rel = rel < -64 ? -64 : (rel > 64 ? 64 : rel);
                    float x = S[sub][r] + qp[wq * 16 + row_l][rel + 64];
                    u32 bit = (u32)(wr >> (sub * 4)) & 1u;
                    S[sub][r] = bit ? -1e30f : x;
                }
            }
#pragma unroll
            for (int r = 0; r < 4; ++r) {
                float rmax = fmaxf(fmaxf(S[0][r], S[1][r]), fmaxf(S[2][r], S[3][r]));
                rmax = fmaxf(rmax, __shfl_xor(rmax, 1));
                rmax = fmaxf(rmax, __shfl_xor(rmax, 2));
                rmax = fmaxf(rmax, __shfl_xor(rmax, 4));
                rmax = fmaxf(rmax, __shfl_xor(rmax, 8));
                m_new[r] = fmaxf(m_run[r], rmax);
                ofs[r]   = m_new[r];
                need |= (m_new[r] > m_run[r]);
            }
        }

        // --- rescale only when a max actually rose -------------------------
        if (__any(need)) {
#pragma unroll
            for (int r = 0; r < 4; ++r) {
                float alpha = fexp2(m_run[r] - m_new[r]);
                l_run[r] *= alpha;
#pragma unroll
                for (int d = 0; d < 4; ++d) O[d][r] *= alpha;
            }
        }
#pragma unroll
        for (int r = 0; r < 4; ++r) {
            m_run[r] = m_new[r];
            float rs = 0.f;
#pragma unroll
            for (int sub = 0; sub < 4; ++sub) {
                float e = fexp2(S[sub][r] - ofs[r]);  // masked -> 0
                rs += e;
                plds[wave][quad * 4 + r][sub * 16 + c16] = f2bf(e);
            }
            rs += __shfl_xor(rs, 1);
            rs += __shfl_xor(rs, 2);
            rs += __shfl_xor(rs, 4);
            rs += __shfl_xor(rs, 8);
            l_run[r] += rs;
        }

        // --- P (A-layout from per-wave LDS) and PV accumulate --------------
        bf16x8 pA0 = *reinterpret_cast<bf16x8*>(&plds[wave][c16][quad * 8]);
        bf16x8 pA1 = *reinterpret_cast<bf16x8*>(&plds[wave][c16][32 + quad * 8]);
        __builtin_amdgcn_s_setprio(1);
#pragma unroll
        for (int d = 0; d < 4; ++d) {
            bf16x8 vf1 = ldg8(vtb_base + (size_t)(d * 16 + c16) * SEQ + k0 + 32 + quad * 8);
            O[d] = __builtin_amdgcn_mfma_f32_16x16x32_bf16(pA0, vf0[d], O[d], 0, 0, 0);
            O[d] = __builtin_amdgcn_mfma_f32_16x16x32_bf16(pA1, vf1, O[d], 0, 0, 0);
        }
        __builtin_amdgcn_s_setprio(0);
    }

    // --- flash-merge the two K-halves (combine buffer overlays dead qp) ----
    __syncthreads();   // everyone done reading qp
    float* cmb = &qp[0][0];
    const int cbase = (wq * 64 + lane) * 24;
    if (wk == 1) {
#pragma unroll
        for (int r = 0; r < 4; ++r) {
            cmb[cbase + r]     = m_run[r];
            cmb[cbase + 4 + r] = l_run[r];
        }
#pragma unroll
        for (int d = 0; d < 4; ++d)
#pragma unroll
            for (int r = 0; r < 4; ++r)
                cmb[cbase + 8 + d * 4 + r] = O[d][r];
    }
    __syncthreads();
    if (wk == 0) {
        float* ob = outg + ((size_t)b * SEQ + q0) * DIM;
#pragma unroll
        for (int r = 0; r < 4; ++r) {
            float m1 = cmb[cbase + r];
            float l1 = cmb[cbase + 4 + r];
            float mm = fmaxf(m_run[r], m1);
            float a0 = fexp2(m_run[r] - mm);
            float a1 = fexp2(m1 - mm);
            float inv = 1.f / (l_run[r] * a0 + l1 * a1);
            int row_l = wq * 16 + quad * 4 + r;
#pragma unroll
            for (int d = 0; d < 4; ++d) {
                float o = O[d][r] * a0 + cmb[cbase + 8 + d * 4 + r] * a1;
                ob[(size_t)row_l * DIM + d * 16 + c16] = o * inv;
            }
        }
    }
}

// ---------------------------------------------------------------------------
// Fallback path kernels (workspace too small for the fast path).
// ---------------------------------------------------------------------------
__global__ __launch_bounds__(256) void vt_kernel(const float* __restrict__ v,
                                                 u16* __restrict__ vt) {
    __shared__ u16 tile[64][72];
    const int b  = blockIdx.y;
    const int k0 = blockIdx.x * 64;
    const int t  = threadIdx.x;
    const float* vb  = v  + (size_t)b * SEQ * DIM;
    u16*         vtb = vt + (size_t)b * DIM * SEQ;

    {
        int kk = t >> 2;
        int d0 = (t & 3) * 16;
        const float* src = vb + (size_t)(k0 + kk) * DIM + d0;
        u16 tmp[16];
#pragma unroll
        for (int i = 0; i < 4; ++i) {
            f32x4 a = *reinterpret_cast<const f32x4*>(src + i * 4);
            tmp[i * 4 + 0] = f2bf(a[0]); tmp[i * 4 + 1] = f2bf(a[1]);
            tmp[i * 4 + 2] = f2bf(a[2]); tmp[i * 4 + 3] = f2bf(a[3]);
        }
        *reinterpret_cast<u32x4*>(&tile[kk][d0])     = *reinterpret_cast<u32x4*>(tmp);
        *reinterpret_cast<u32x4*>(&tile[kk][d0 + 8]) = *reinterpret_cast<u32x4*>(tmp + 8);
    }
    __syncthreads();
#pragma unroll
    for (int i = 0; i < 2; ++i) {
        int d  = t / 8 + i * 32;
        int ks = (t % 8) * 8;
        u16 tmp[8];
#pragma unroll
        for (int j = 0; j < 8; ++j) tmp[j] = tile[ks + j][d];
        *reinterpret_cast<u32x4*>(vtb + (size_t)d * SEQ + k0 + ks) =
            *reinterpret_cast<u32x4*>(tmp);
    }
}

template <bool USE_VT>
__global__ __launch_bounds__(256, 2) void attn_kernel(
    const float* __restrict__ qg, const float* __restrict__ kg,
    const void* __restrict__ vgv, const int* __restrict__ maskg,
    const float* __restrict__ ptg, float* __restrict__ outg) {
    __shared__ float qp[64][132];
    __shared__ int   mlds[4][16][68];
    __shared__ u16   plds[4][16][72];

    const int b    = blockIdx.y;
    const int q0   = blockIdx.x * 64;
    const int tid  = threadIdx.x;
    const int wave = tid >> 6;
    const int lane = tid & 63;
    const int quad = lane >> 4;
    const int c16  = lane & 15;

    const float* qb = qg + ((size_t)b * SEQ + q0) * DIM;
    const float* kb = kg + (size_t)b * SEQ * DIM;
    const int*   mb = maskg + ((size_t)b * SEQ + q0) * SEQ;

    const bf16x8 qA0 = cvt8(qb + (size_t)(wave * 16 + c16) * DIM + quad * 8);
    const bf16x8 qA1 = cvt8(qb + (size_t)(wave * 16 + c16) * DIM + 32 + quad * 8);

    for (int jt = 0; jt < 9; ++jt) {
        int j0 = jt * 16;
        int jr = min(j0 + c16, 128);
        bf16x8 b0 = cvt8(ptg + (size_t)jr * DIM + quad * 8);
        bf16x8 b1 = cvt8(ptg + (size_t)jr * DIM + 32 + quad * 8);
        f32x4 acc = {0.f, 0.f, 0.f, 0.f};
        acc = __builtin_amdgcn_mfma_f32_16x16x32_bf16(qA0, b0, acc, 0, 0, 0);
        acc = __builtin_amdgcn_mfma_f32_16x16x32_bf16(qA1, b1, acc, 0, 0, 0);
        int jcol = j0 + c16;
        if (jcol <= 128) {
#pragma unroll
            for (int r = 0; r < 4; ++r)
                qp[wave * 16 + quad * 4 + r][jcol] = acc[r];
        }
    }

    float m_run[4], l_run[4];
    f32x4 O[4];
#pragma unroll
    for (int r = 0; r < 4; ++r) { m_run[r] = -1e30f; l_run[r] = 0.f; }
#pragma unroll
    for (int d = 0; d < 4; ++d) O[d] = f32x4{0.f, 0.f, 0.f, 0.f};

#pragma unroll 1
    for (int kt = 0; kt < NKT; ++kt) {
        const int k0 = kt * 64;
        {
            int row_l = lane >> 2;
            const int* mrow = mb + (size_t)(wave * 16 + row_l) * SEQ + k0;
#pragma unroll
            for (int i = 0; i < 4; ++i) {
                int seg = (lane & 3) + i * 4;
                *reinterpret_cast<u32x4*>(&mlds[wave][row_l][seg * 4]) =
                    *reinterpret_cast<const u32x4*>(mrow + seg * 4);
            }
        }

        f32x4 S[4];
#pragma unroll
        for (int sub = 0; sub < 4; ++sub) {
            const float* kr = kb + (size_t)(k0 + sub * 16 + c16) * DIM;
            bf16x8 kb0 = cvt8(kr + quad * 8);
            bf16x8 kb1 = cvt8(kr + 32 + quad * 8);
            f32x4 acc = {0.f, 0.f, 0.f, 0.f};
            acc = __builtin_amdgcn_mfma_f32_16x16x32_bf16(qA0, kb0, acc, 0, 0, 0);
            acc = __builtin_amdgcn_mfma_f32_16x16x32_bf16(qA1, kb1, acc, 0, 0, 0);
            S[sub] = acc;
        }

        float sv[4][4];
#pragma unroll
        for (int sub = 0; sub < 4; ++sub) {
#pragma unroll
            for (int r = 0; r < 4; ++r) {
                int row_l = quad * 4 + r;
                int row_g = q0 + wave * 16 + row_l;
                int col_g = k0 + sub * 16 + c16;
                int rel = col_g - row_g;
                rel = rel < -64 ? -64 : (rel > 64 ? 64 : rel);
                float x = (S[sub][r] + qp[wave * 16 + row_l][rel + 64]) * 0.125f;
                int mv = mlds[wave][row_l][sub * 16 + c16];
                sv[sub][r] = mv ? -1e30f : x;
            }
        }

        float m_new[4], alpha[4];
#pragma unroll
        for (int r = 0; r < 4; ++r) {
            float rmax = fmaxf(fmaxf(sv[0][r], sv[1][r]), fmaxf(sv[2][r], sv[3][r]));
            rmax = fmaxf(rmax, __shfl_xor(rmax, 1));
            rmax = fmaxf(rmax, __shfl_xor(rmax, 2));
            rmax = fmaxf(rmax, __shfl_xor(rmax, 4));
            rmax = fmaxf(rmax, __shfl_xor(rmax, 8));
            m_new[r] = fmaxf(m_run[r], rmax);
            alpha[r] = __expf(m_run[r] - m_new[r]);
            m_run[r] = m_new[r];
        }
#pragma unroll
        for (int r = 0; r < 4; ++r) {
            float rs = 0.f;
#pragma unroll
            for (int sub = 0; sub < 4; ++sub) {
                float e = __expf(sv[sub][r] - m_new[r]);
                rs += e;
                plds[wave][quad * 4 + r][sub * 16 + c16] = f2bf(e);
            }
            rs += __shfl_xor(rs, 1);
            rs += __shfl_xor(rs, 2);
            rs += __shfl_xor(rs, 4);
            rs += __shfl_xor(rs, 8);
            l_run[r] = l_run[r] * alpha[r] + rs;
#pragma unroll
            for (int d = 0; d < 4; ++d) O[d][r] *= alpha[r];
        }

        bf16x8 pA0 = *reinterpret_cast<bf16x8*>(&plds[wave][c16][quad * 8]);
        bf16x8 pA1 = *reinterpret_cast<bf16x8*>(&plds[wave][c16][32 + quad * 8]);
#pragma unroll
        for (int d = 0; d < 4; ++d) {
            bf16x8 vb0, vb1;
            if (USE_VT) {
                const u16* vtb = (const u16*)vgv + (size_t)b * DIM * SEQ +
                                 (size_t)(d * 16 + c16) * SEQ + k0;
                vb0 = ldg8(vtb + quad * 8);
                vb1 = ldg8(vtb + 32 + quad * 8);
            } else {
                u16 t0[8], t1[8];
                const float* vbase = (const float*)vgv +
                                     ((size_t)b * SEQ + k0) * DIM + d * 16 + c16;
#pragma unroll
                for (int j = 0; j < 8; ++j) {
                    t0[j] = f2bf(vbase[(size_t)(quad * 8 + j) * DIM]);
                    t1[j] = f2bf(vbase[(size_t)(32 + quad * 8 + j) * DIM]);
                }
                vb0 = __builtin_bit_cast(bf16x8, *reinterpret_cast<u32x4*>(t0));
                vb1 = __builtin_bit_cast(bf16x8, *reinterpret_cast<u32x4*>(t1));
            }
            O[d] = __builtin_amdgcn_mfma_f32_16x16x32_bf16(pA0, vb0, O[d], 0, 0, 0);
            O[d] = __builtin_amdgcn_mfma_f32_16x16x32_bf16(pA1, vb1, O[d], 0, 0, 0);
        }
    }

    float* ob = outg + ((size_t)b * SEQ + q0) * DIM;
#pragma unroll
    for (int r = 0; r < 4; ++r) {
        float inv = 1.f / l_run[r];
        int row_l = wave * 16 + quad * 4 + r;
#pragma unroll
        for (int d = 0; d < 4; ++d)
            ob[(size_t)row_l * DIM + d * 16 + c16] = O[d][r] * inv;
    }
}

// ---------------------------------------------------------------------------
extern "C" void kernel_launch(void* const* d_in, const int* in_sizes, int n_in,
                              void* d_out, int out_size, void* d_ws, size_t ws_size,
                              hipStream_t stream) {
    const float* q    = (const float*)d_in[0];
    const float* k    = (const float*)d_in[1];
    const float* v    = (const float*)d_in[2];
    const int*   mask = (const int*)d_in[3];
    const float* pt   = (const float*)d_in[4];
    float* out        = (float*)d_out;

    const size_t vt_bytes = (size_t)BATCH * SEQ * DIM * sizeof(u16);   // 4 MB
    const size_t kb_bytes = (size_t)BATCH * SEQ * DIM * sizeof(u16);   // 4 MB
    const size_t mb_bytes = (size_t)BATCH * SEQ * 16 * sizeof(u64);    // 4 MB
    dim3 grid(SEQ / 64, BATCH);

    if (ws_size >= vt_bytes + kb_bytes + mb_bytes) {
        u16* vt  = (u16*)d_ws;
        u16* kb  = (u16*)((char*)d_ws + vt_bytes);
        u64* mb2 = (u64*)((char*)d_ws + vt_bytes + kb_bytes);
        prep_kernel<<<dim3(8192), 256, 0, stream>>>(k, v, mask, kb, vt, mb2);
        attn_fast3<<<grid, 512, 0, stream>>>(q, kb, vt, mb2, pt, out);
    } else if (ws_size >= vt_bytes) {
        u16* vt = (u16*)d_ws;
        vt_kernel<<<grid, 256, 0, stream>>>(v, vt);
        attn_kernel<true><<<grid, 256, 0, stream>>>(q, k, (const void*)vt, mask, pt, out);
    } else {
        attn_kernel<false><<<grid, 256, 0, stream>>>(q, k, (const void*)v, mask, pt, out);
    }
}

// Round 4
// 292.298 us; speedup vs baseline: 1.2321x; 1.2321x over previous
//
#include <hip/hip_runtime.h>
#include <stdint.h>

#define BATCH 32
#define SEQ   1024
#define DIM   64
#define NKT   (SEQ / 64)

typedef uint16_t u16;
typedef uint32_t u32;
typedef unsigned long long u64;
typedef __attribute__((ext_vector_type(8))) __bf16 bf16x8;
typedef __attribute__((ext_vector_type(4))) float  f32x4;
typedef __attribute__((ext_vector_type(4))) u32    u32x4;

__device__ __forceinline__ float fexp2(float x) {
#if __has_builtin(__builtin_amdgcn_exp2f)
    return __builtin_amdgcn_exp2f(x);
#else
    return exp2f(x);
#endif
}

__device__ __forceinline__ u16 f2bf(float f) {
    u32 x = __builtin_bit_cast(u32, f);
    x += 0x7FFFu + ((x >> 16) & 1u);   // round-to-nearest-even
    return (u16)(x >> 16);
}

// 8 contiguous f32 -> bf16x8 fragment (RNE)
__device__ __forceinline__ bf16x8 cvt8(const float* __restrict__ p) {
    f32x4 a = *reinterpret_cast<const f32x4*>(p);
    f32x4 b = *reinterpret_cast<const f32x4*>(p + 4);
    u16 t[8];
    t[0] = f2bf(a[0]); t[1] = f2bf(a[1]); t[2] = f2bf(a[2]); t[3] = f2bf(a[3]);
    t[4] = f2bf(b[0]); t[5] = f2bf(b[1]); t[6] = f2bf(b[2]); t[7] = f2bf(b[3]);
    return __builtin_bit_cast(bf16x8, *reinterpret_cast<u32x4*>(t));
}

// scaled variant (scale folded into the bf16 fragment)
__device__ __forceinline__ bf16x8 cvt8s(const float* __restrict__ p, float s) {
    f32x4 a = *reinterpret_cast<const f32x4*>(p);
    f32x4 b = *reinterpret_cast<const f32x4*>(p + 4);
    u16 t[8];
    t[0] = f2bf(a[0] * s); t[1] = f2bf(a[1] * s); t[2] = f2bf(a[2] * s); t[3] = f2bf(a[3] * s);
    t[4] = f2bf(b[0] * s); t[5] = f2bf(b[1] * s); t[6] = f2bf(b[2] * s); t[7] = f2bf(b[3] * s);
    return __builtin_bit_cast(bf16x8, *reinterpret_cast<u32x4*>(t));
}

__device__ __forceinline__ bf16x8 ldg8(const u16* p) {
    u32x4 u = *reinterpret_cast<const u32x4*>(p);
    return __builtin_bit_cast(bf16x8, u);
}

// ---------------------------------------------------------------------------
// Fused prepass (4096 blocks):
//  - mask int32 [B][S][S] -> ballot-native bitwords.
//    Layout: bits[row*16 + g*4 + i], g = 256-col group, i = col%4.
//    Word i bit l = mask[row][g*256 + 4l + i].
//    One wave = TWO rows; all 8 group-loads issued upfront (8-deep MLP).
//  - blocks < 512 additionally: V f32 -> Vt bf16 [B][D][S] (LDS transpose)
//    and K f32 -> bf16 row-major.
// ---------------------------------------------------------------------------
__global__ __launch_bounds__(256) void prep_kernel(
    const float* __restrict__ kg, const float* __restrict__ vg,
    const int* __restrict__ mask, u16* __restrict__ kb,
    u16* __restrict__ vtb_, u64* __restrict__ bits) {
    __shared__ u16 tile[64][72];
    const int t    = threadIdx.x;
    const int wave = t >> 6;
    const int lane = t & 63;
    const int rowA = (blockIdx.x * 4 + wave) * 2;   // 0..32766
    const int rowB = rowA + 1;

    // ---- mask packing: 2 rows x 4 groups, all loads in flight upfront -----
    const int* mA = mask + (size_t)rowA * SEQ + lane * 4;
    const int* mB = mask + (size_t)rowB * SEQ + lane * 4;
    u32x4 a0 = *reinterpret_cast<const u32x4*>(mA);
    u32x4 a1 = *reinterpret_cast<const u32x4*>(mA + 256);
    u32x4 a2 = *reinterpret_cast<const u32x4*>(mA + 512);
    u32x4 a3 = *reinterpret_cast<const u32x4*>(mA + 768);
    u32x4 c0 = *reinterpret_cast<const u32x4*>(mB);
    u32x4 c1 = *reinterpret_cast<const u32x4*>(mB + 256);
    u32x4 c2 = *reinterpret_cast<const u32x4*>(mB + 512);
    u32x4 c3 = *reinterpret_cast<const u32x4*>(mB + 768);

#define MPROC(x, row, g)                                                      \
    {                                                                         \
        int nib = (x[0] != 0) | ((x[1] != 0) << 1) |                          \
                  ((x[2] != 0) << 2) | ((x[3] != 0) << 3);                    \
        u64 b0 = __ballot(nib & 1);                                           \
        u64 b1 = __ballot(nib & 2);                                           \
        u64 b2 = __ballot(nib & 4);                                           \
        u64 b3 = __ballot(nib & 8);                                           \
        if (lane < 4) {                                                       \
            u64 w = (lane == 0) ? b0 : (lane == 1) ? b1 : (lane == 2) ? b2 : b3; \
            bits[(size_t)(row) * 16 + (g) * 4 + lane] = w;                    \
        }                                                                     \
    }
    MPROC(a0, rowA, 0) MPROC(a1, rowA, 1) MPROC(a2, rowA, 2) MPROC(a3, rowA, 3)
    MPROC(c0, rowB, 0) MPROC(c1, rowB, 1) MPROC(c2, rowB, 2) MPROC(c3, rowB, 3)
#undef MPROC

    // ---- V transpose + K bf16 for the first 512 blocks --------------------
    if (blockIdx.x < 512) {
        const int b  = blockIdx.x >> 4;
        const int k0 = (blockIdx.x & 15) * 64;

        // K f32 -> bf16 row-major (64x64 tile)
        {
            int kk = t >> 2;
            int d0 = (t & 3) * 16;
            const float* src = kg + ((size_t)b * SEQ + k0 + kk) * DIM + d0;
            u16 tmp[16];
#pragma unroll
            for (int i = 0; i < 4; ++i) {
                f32x4 a = *reinterpret_cast<const f32x4*>(src + i * 4);
                tmp[i * 4 + 0] = f2bf(a[0]); tmp[i * 4 + 1] = f2bf(a[1]);
                tmp[i * 4 + 2] = f2bf(a[2]); tmp[i * 4 + 3] = f2bf(a[3]);
            }
            u16* dst = kb + ((size_t)b * SEQ + k0 + kk) * DIM + d0;
            *reinterpret_cast<u32x4*>(dst)     = *reinterpret_cast<u32x4*>(tmp);
            *reinterpret_cast<u32x4*>(dst + 8) = *reinterpret_cast<u32x4*>(tmp + 8);
        }

        // V transpose via LDS
        const float* vb  = vg  + (size_t)b * SEQ * DIM;
        u16*         vtb = vtb_ + (size_t)b * DIM * SEQ;
        {
            int kk = t >> 2;
            int d0 = (t & 3) * 16;
            const float* src = vb + (size_t)(k0 + kk) * DIM + d0;
            u16 tmp[16];
#pragma unroll
            for (int i = 0; i < 4; ++i) {
                f32x4 a = *reinterpret_cast<const f32x4*>(src + i * 4);
                tmp[i * 4 + 0] = f2bf(a[0]); tmp[i * 4 + 1] = f2bf(a[1]);
                tmp[i * 4 + 2] = f2bf(a[2]); tmp[i * 4 + 3] = f2bf(a[3]);
            }
            *reinterpret_cast<u32x4*>(&tile[kk][d0])     = *reinterpret_cast<u32x4*>(tmp);
            *reinterpret_cast<u32x4*>(&tile[kk][d0 + 8]) = *reinterpret_cast<u32x4*>(tmp + 8);
        }
        __syncthreads();
#pragma unroll
        for (int i = 0; i < 2; ++i) {
            int d  = t / 8 + i * 32;
            int ks = (t % 8) * 8;
            u16 tmp[8];
#pragma unroll
            for (int j = 0; j < 8; ++j) tmp[j] = tile[ks + j][d];
            *reinterpret_cast<u32x4*>(vtb + (size_t)d * SEQ + k0 + ks) =
                *reinterpret_cast<u32x4*>(tmp);
        }
    }
}

// ---------------------------------------------------------------------------
// Fused rel-pos attention, split-K across wave pairs.
// 512 threads = 8 waves: wave (wq = w&3, wk = w>>2).
// vs round 3: __launch_bounds__(512,2) (256-VGPR cap) + NAMED prefetch
// registers (no arrays, unconditional wrapped-index loads) so K/V prefetch
// lives in VGPRs, not scratch.  Far-tile shortcut kept.
// ---------------------------------------------------------------------------
__global__ __launch_bounds__(512, 2) void attn_fast4(
    const float* __restrict__ qg, const u16* __restrict__ kbf,
    const u16* __restrict__ vt, const u64* __restrict__ mbits,
    const float* __restrict__ ptg, float* __restrict__ outg) {
    __shared__ float qp[64][132];        // 33792 B; reused as combine buffer
    __shared__ u16   plds[8][16][72];    // 18432 B, per-wave P tile

    const int b    = blockIdx.y;
    const int q0   = blockIdx.x * 64;
    const int tid  = threadIdx.x;
    const int wave = tid >> 6;
    const int lane = tid & 63;
    const int wq   = wave & 3;
    const int wk   = wave >> 2;
    const int quad = lane >> 4;
    const int c16  = lane & 15;

    const float SC = 0.125f * 1.44269504088896340736f;  // 1/8 * log2(e)

    const float* qb = qg + ((size_t)b * SEQ + q0) * DIM;

    // Q A-fragments, pre-scaled (exp2 space)
    const bf16x8 qA0 = cvt8s(qb + (size_t)(wq * 16 + c16) * DIM + quad * 8, SC);
    const bf16x8 qA1 = cvt8s(qb + (size_t)(wq * 16 + c16) * DIM + 32 + quad * 8, SC);

    // mask bitwords for this wave's rows and its two 4-kt groups (8 loads, L2)
    const size_t rowbase = (size_t)b * SEQ + q0 + wq * 16 + quad * 4;
    u64 w2[2][4];
#pragma unroll
    for (int gg = 0; gg < 2; ++gg)
#pragma unroll
        for (int r = 0; r < 4; ++r)
            w2[gg][r] = mbits[((rowbase + r) * 4 + (wk * 2 + gg)) * 4 + (c16 & 3)];

    // qp[64][129] = (SC*Q)(64x64) . pos_table^T ; jt tiles split across wk
    {
        const int jt0 = wk ? 5 : 0, jt1 = wk ? 9 : 5;
        for (int jt = jt0; jt < jt1; ++jt) {
            int j0 = jt * 16;
            int jr = min(j0 + c16, 128);
            bf16x8 b0 = cvt8(ptg + (size_t)jr * DIM + quad * 8);
            bf16x8 b1 = cvt8(ptg + (size_t)jr * DIM + 32 + quad * 8);
            f32x4 acc = {0.f, 0.f, 0.f, 0.f};
            acc = __builtin_amdgcn_mfma_f32_16x16x32_bf16(qA0, b0, acc, 0, 0, 0);
            acc = __builtin_amdgcn_mfma_f32_16x16x32_bf16(qA1, b1, acc, 0, 0, 0);
            int jcol = j0 + c16;
            if (jcol <= 128) {
#pragma unroll
                for (int r = 0; r < 4; ++r)
                    qp[wq * 16 + quad * 4 + r][jcol] = acc[r];
            }
        }
    }
    __syncthreads();   // qp complete (both halves)

    // per-row saturation constants (left / right), one broadcast LDS read each
    float cL[4], cR[4];
#pragma unroll
    for (int r = 0; r < 4; ++r) {
        cL[r] = qp[wq * 16 + quad * 4 + r][0];
        cR[r] = qp[wq * 16 + quad * 4 + r][128];
    }

    const u16* kb_base  = kbf + (size_t)b * SEQ * DIM;
    const u16* vtb_base = vt  + (size_t)b * DIM * SEQ;
    const int  row_min  = q0 + wq * 16;

    float m_run[4], l_run[4];
    f32x4 O[4];
#pragma unroll
    for (int r = 0; r < 4; ++r) { m_run[r] = -1e30f; l_run[r] = 0.f; }
#pragma unroll
    for (int d = 0; d < 4; ++d) O[d] = f32x4{0.f, 0.f, 0.f, 0.f};

    const int ktbase = wk * 8;

    // K fragments for the whole 64-col tile, in NAMED registers (loop-carried)
    bf16x8 k0a, k0b, k1a, k1b, k2a, k2b, k3a, k3b;
#define KLOAD(KT)                                                            \
    {                                                                        \
        const u16* krb_ = kb_base + (size_t)((KT) * 64 + c16) * DIM;         \
        k0a = ldg8(krb_ + quad * 8);                                         \
        k0b = ldg8(krb_ + 32 + quad * 8);                                    \
        k1a = ldg8(krb_ + 16 * DIM + quad * 8);                              \
        k1b = ldg8(krb_ + 16 * DIM + 32 + quad * 8);                         \
        k2a = ldg8(krb_ + 32 * DIM + quad * 8);                              \
        k2b = ldg8(krb_ + 32 * DIM + 32 + quad * 8);                         \
        k3a = ldg8(krb_ + 48 * DIM + quad * 8);                              \
        k3b = ldg8(krb_ + 48 * DIM + 32 + quad * 8);                         \
    }
    KLOAD(ktbase)

#pragma unroll 1
    for (int j = 0; j < 8; ++j) {
        const int kt   = ktbase + j;
        const int k0   = kt * 64;
        const int j_gg = j >> 2;
        const int j_t  = j & 3;

        // --- S = (SC*Q) . K^T from register fragments ----------------------
        f32x4 S[4];
        __builtin_amdgcn_s_setprio(1);
        S[0] = __builtin_amdgcn_mfma_f32_16x16x32_bf16(
            qA1, k0b, __builtin_amdgcn_mfma_f32_16x16x32_bf16(
                          qA0, k0a, f32x4{0.f, 0.f, 0.f, 0.f}, 0, 0, 0), 0, 0, 0);
        S[1] = __builtin_amdgcn_mfma_f32_16x16x32_bf16(
            qA1, k1b, __builtin_amdgcn_mfma_f32_16x16x32_bf16(
                          qA0, k1a, f32x4{0.f, 0.f, 0.f, 0.f}, 0, 0, 0), 0, 0, 0);
        S[2] = __builtin_amdgcn_mfma_f32_16x16x32_bf16(
            qA1, k2b, __builtin_amdgcn_mfma_f32_16x16x32_bf16(
                          qA0, k2a, f32x4{0.f, 0.f, 0.f, 0.f}, 0, 0, 0), 0, 0, 0);
        S[3] = __builtin_amdgcn_mfma_f32_16x16x32_bf16(
            qA1, k3b, __builtin_amdgcn_mfma_f32_16x16x32_bf16(
                          qA0, k3a, f32x4{0.f, 0.f, 0.f, 0.f}, 0, 0, 0), 0, 0, 0);
        __builtin_amdgcn_s_setprio(0);

        // --- prefetch next kt's K (wrapped index; hidden under softmax+PV) -
        KLOAD(ktbase + ((j + 1) & 7))

        // --- issue current V loads early (consumed by PV after softmax) ----
        bf16x8 v0a, v0b, v1a, v1b, v2a, v2b, v3a, v3b;
        {
            const u16* vrb_ = vtb_base + (size_t)c16 * SEQ + k0 + quad * 8;
            v0a = ldg8(vrb_);                 v0b = ldg8(vrb_ + 32);
            v1a = ldg8(vrb_ + 16 * SEQ);      v1b = ldg8(vrb_ + 16 * SEQ + 32);
            v2a = ldg8(vrb_ + 32 * SEQ);      v2b = ldg8(vrb_ + 32 * SEQ + 32);
            v3a = ldg8(vrb_ + 48 * SEQ);      v3b = ldg8(vrb_ + 48 * SEQ + 32);
        }

        // --- logits + row-max; far tiles skip the qp gather entirely -------
        const bool farL = (k0 + 127 <= row_min);
        const bool farR = (k0 >= row_min + 79);
        float m_new[4], ofs[4];
        bool need = false;

        if (farL | farR) {
#pragma unroll
            for (int r = 0; r < 4; ++r) {
                const u64 wr = w2[j_gg][r] >> (j_t * 16 + (c16 >> 2));
#pragma unroll
                for (int sub = 0; sub < 4; ++sub) {
                    u32 bit = (u32)(wr >> (sub * 4)) & 1u;
                    S[sub][r] = bit ? -1e30f : S[sub][r];
                }
            }
#pragma unroll
            for (int r = 0; r < 4; ++r) {
                float c = farL ? cL[r] : cR[r];
                float rmax = fmaxf(fmaxf(S[0][r], S[1][r]), fmaxf(S[2][r], S[3][r]));
                rmax = fmaxf(rmax, __shfl_xor(rmax, 1));
                rmax = fmaxf(rmax, __shfl_xor(rmax, 2));
                rmax = fmaxf(rmax, __shfl_xor(rmax, 4));
                rmax = fmaxf(rmax, __shfl_xor(rmax, 8));
                m_new[r] = fmaxf(m_run[r], rmax + c);
                ofs[r]   = m_new[r] - c;          // e = exp2(S - (m_new - c))
                need |= (m_new[r] > m_run[r]);
            }
        } else {
            // near-diagonal tile: per-element qp gather (<=3 of 8 tiles)
#pragma unroll
            for (int r = 0; r < 4; ++r) {
                const int row_l = quad * 4 + r;
                const int row_g = row_min + row_l;
                const u64 wr = w2[j_gg][r] >> (j_t * 16 + (c16 >> 2));
#pragma unroll
                for (int sub = 0; sub < 4; ++sub) {
                    int col_g = k0 + sub * 16 + c16;
                    int rel = col_g - row_g;
                    rel = rel < -64 ? -64 : (rel > 64 ? 64 : rel);
                    float x = S[sub][r] + qp[wq * 16 + row_l][rel + 64];
                    u32 bit = (u32)(wr >> (sub * 4)) & 1u;
                    S[sub][r] = bit ? -1e30f : x;
                }
            }
#pragma unroll
            for (int r = 0; r < 4; ++r) {
                float rmax = fmaxf(fmaxf(S[0][r], S[1][r]), fmaxf(S[2][r], S[3][r]));
                rmax = fmaxf(rmax, __shfl_xor(rmax, 1));
                rmax = fmaxf(rmax, __shfl_xor(rmax, 2));
                rmax = fmaxf(rmax, __shfl_xor(rmax, 4));
                rmax = fmaxf(rmax, __shfl_xor(rmax, 8));
                m_new[r] = fmaxf(m_run[r], rmax);
                ofs[r]   = m_new[r];
                need |= (m_new[r] > m_run[r]);
            }
        }

        // --- rescale only when a max actually rose -------------------------
        if (__any(need)) {
#pragma unroll
            for (int r = 0; r < 4; ++r) {
                float alpha = fexp2(m_run[r] - m_new[r]);
                l_run[r] *= alpha;
#pragma unroll
                for (int d = 0; d < 4; ++d) O[d][r] *= alpha;
            }
        }
#pragma unroll
        for (int r = 0; r < 4; ++r) {
            m_run[r] = m_new[r];
            float rs = 0.f;
#pragma unroll
            for (int sub = 0; sub < 4; ++sub) {
                float e = fexp2(S[sub][r] - ofs[r]);  // masked -> 0
                rs += e;
                plds[wave][quad * 4 + r][sub * 16 + c16] = f2bf(e);
            }
            rs += __shfl_xor(rs, 1);
            rs += __shfl_xor(rs, 2);
            rs += __shfl_xor(rs, 4);
            rs += __shfl_xor(rs, 8);
            l_run[r] += rs;
        }

        // --- P (A-layout from per-wave LDS) and PV accumulate --------------
        bf16x8 pA0 = *reinterpret_cast<bf16x8*>(&plds[wave][c16][quad * 8]);
        bf16x8 pA1 = *reinterpret_cast<bf16x8*>(&plds[wave][c16][32 + quad * 8]);
        __builtin_amdgcn_s_setprio(1);
        O[0] = __builtin_amdgcn_mfma_f32_16x16x32_bf16(
            pA1, v0b, __builtin_amdgcn_mfma_f32_16x16x32_bf16(pA0, v0a, O[0], 0, 0, 0), 0, 0, 0);
        O[1] = __builtin_amdgcn_mfma_f32_16x16x32_bf16(
            pA1, v1b, __builtin_amdgcn_mfma_f32_16x16x32_bf16(pA0, v1a, O[1], 0, 0, 0), 0, 0, 0);
        O[2] = __builtin_amdgcn_mfma_f32_16x16x32_bf16(
            pA1, v2b, __builtin_amdgcn_mfma_f32_16x16x32_bf16(pA0, v2a, O[2], 0, 0, 0), 0, 0, 0);
        O[3] = __builtin_amdgcn_mfma_f32_16x16x32_bf16(
            pA1, v3b, __builtin_amdgcn_mfma_f32_16x16x32_bf16(pA0, v3a, O[3], 0, 0, 0), 0, 0, 0);
        __builtin_amdgcn_s_setprio(0);
    }
#undef KLOAD

    // --- flash-merge the two K-halves (combine buffer overlays dead qp) ----
    __syncthreads();   // everyone done reading qp
    float* cmb = &qp[0][0];
    const int cbase = (wq * 64 + lane) * 24;
    if (wk == 1) {
#pragma unroll
        for (int r = 0; r < 4; ++r) {
            cmb[cbase + r]     = m_run[r];
            cmb[cbase + 4 + r] = l_run[r];
        }
#pragma unroll
        for (int d = 0; d < 4; ++d)
#pragma unroll
            for (int r = 0; r < 4; ++r)
                cmb[cbase + 8 + d * 4 + r] = O[d][r];
    }
    __syncthreads();
    if (wk == 0) {
        float* ob = outg + ((size_t)b * SEQ + q0) * DIM;
#pragma unroll
        for (int r = 0; r < 4; ++r) {
            float m1 = cmb[cbase + r];
            float l1 = cmb[cbase + 4 + r];
            float mm = fmaxf(m_run[r], m1);
            float a0 = fexp2(m_run[r] - mm);
            float a1 = fexp2(m1 - mm);
            float inv = 1.f / (l_run[r] * a0 + l1 * a1);
            int row_l = wq * 16 + quad * 4 + r;
#pragma unroll
            for (int d = 0; d < 4; ++d) {
                float o = O[d][r] * a0 + cmb[cbase + 8 + d * 4 + r] * a1;
                ob[(size_t)row_l * DIM + d * 16 + c16] = o * inv;
            }
        }
    }
}

// ---------------------------------------------------------------------------
// Fallback path kernels (workspace too small for the fast path).
// ---------------------------------------------------------------------------
__global__ __launch_bounds__(256) void vt_kernel(const float* __restrict__ v,
                                                 u16* __restrict__ vt) {
    __shared__ u16 tile[64][72];
    const int b  = blockIdx.y;
    const int k0 = blockIdx.x * 64;
    const int t  = threadIdx.x;
    const float* vb  = v  + (size_t)b * SEQ * DIM;
    u16*         vtb = vt + (size_t)b * DIM * SEQ;

    {
        int kk = t >> 2;
        int d0 = (t & 3) * 16;
        const float* src = vb + (size_t)(k0 + kk) * DIM + d0;
        u16 tmp[16];
#pragma unroll
        for (int i = 0; i < 4; ++i) {
            f32x4 a = *reinterpret_cast<const f32x4*>(src + i * 4);
            tmp[i * 4 + 0] = f2bf(a[0]); tmp[i * 4 + 1] = f2bf(a[1]);
            tmp[i * 4 + 2] = f2bf(a[2]); tmp[i * 4 + 3] = f2bf(a[3]);
        }
        *reinterpret_cast<u32x4*>(&tile[kk][d0])     = *reinterpret_cast<u32x4*>(tmp);
        *reinterpret_cast<u32x4*>(&tile[kk][d0 + 8]) = *reinterpret_cast<u32x4*>(tmp + 8);
    }
    __syncthreads();
#pragma unroll
    for (int i = 0; i < 2; ++i) {
        int d  = t / 8 + i * 32;
        int ks = (t % 8) * 8;
        u16 tmp[8];
#pragma unroll
        for (int j = 0; j < 8; ++j) tmp[j] = tile[ks + j][d];
        *reinterpret_cast<u32x4*>(vtb + (size_t)d * SEQ + k0 + ks) =
            *reinterpret_cast<u32x4*>(tmp);
    }
}

template <bool USE_VT>
__global__ __launch_bounds__(256, 2) void attn_kernel(
    const float* __restrict__ qg, const float* __restrict__ kg,
    const void* __restrict__ vgv, const int* __restrict__ maskg,
    const float* __restrict__ ptg, float* __restrict__ outg) {
    __shared__ float qp[64][132];
    __shared__ int   mlds[4][16][68];
    __shared__ u16   plds[4][16][72];

    const int b    = blockIdx.y;
    const int q0   = blockIdx.x * 64;
    const int tid  = threadIdx.x;
    const int wave = tid >> 6;
    const int lane = tid & 63;
    const int quad = lane >> 4;
    const int c16  = lane & 15;

    const float* qb = qg + ((size_t)b * SEQ + q0) * DIM;
    const float* kb = kg + (size_t)b * SEQ * DIM;
    const int*   mb = maskg + ((size_t)b * SEQ + q0) * SEQ;

    const bf16x8 qA0 = cvt8(qb + (size_t)(wave * 16 + c16) * DIM + quad * 8);
    const bf16x8 qA1 = cvt8(qb + (size_t)(wave * 16 + c16) * DIM + 32 + quad * 8);

    for (int jt = 0; jt < 9; ++jt) {
        int j0 = jt * 16;
        int jr = min(j0 + c16, 128);
        bf16x8 b0 = cvt8(ptg + (size_t)jr * DIM + quad * 8);
        bf16x8 b1 = cvt8(ptg + (size_t)jr * DIM + 32 + quad * 8);
        f32x4 acc = {0.f, 0.f, 0.f, 0.f};
        acc = __builtin_amdgcn_mfma_f32_16x16x32_bf16(qA0, b0, acc, 0, 0, 0);
        acc = __builtin_amdgcn_mfma_f32_16x16x32_bf16(qA1, b1, acc, 0, 0, 0);
        int jcol = j0 + c16;
        if (jcol <= 128) {
#pragma unroll
            for (int r = 0; r < 4; ++r)
                qp[wave * 16 + quad * 4 + r][jcol] = acc[r];
        }
    }

    float m_run[4], l_run[4];
    f32x4 O[4];
#pragma unroll
    for (int r = 0; r < 4; ++r) { m_run[r] = -1e30f; l_run[r] = 0.f; }
#pragma unroll
    for (int d = 0; d < 4; ++d) O[d] = f32x4{0.f, 0.f, 0.f, 0.f};

#pragma unroll 1
    for (int kt = 0; kt < NKT; ++kt) {
        const int k0 = kt * 64;
        {
            int row_l = lane >> 2;
            const int* mrow = mb + (size_t)(wave * 16 + row_l) * SEQ + k0;
#pragma unroll
            for (int i = 0; i < 4; ++i) {
                int seg = (lane & 3) + i * 4;
                *reinterpret_cast<u32x4*>(&mlds[wave][row_l][seg * 4]) =
                    *reinterpret_cast<const u32x4*>(mrow + seg * 4);
            }
        }

        f32x4 S[4];
#pragma unroll
        for (int sub = 0; sub < 4; ++sub) {
            const float* kr = kb + (size_t)(k0 + sub * 16 + c16) * DIM;
            bf16x8 kb0 = cvt8(kr + quad * 8);
            bf16x8 kb1 = cvt8(kr + 32 + quad * 8);
            f32x4 acc = {0.f, 0.f, 0.f, 0.f};
            acc = __builtin_amdgcn_mfma_f32_16x16x32_bf16(qA0, kb0, acc, 0, 0, 0);
            acc = __builtin_amdgcn_mfma_f32_16x16x32_bf16(qA1, kb1, acc, 0, 0, 0);
            S[sub] = acc;
        }

        float sv[4][4];
#pragma unroll
        for (int sub = 0; sub < 4; ++sub) {
#pragma unroll
            for (int r = 0; r < 4; ++r) {
                int row_l = quad * 4 + r;
                int row_g = q0 + wave * 16 + row_l;
                int col_g = k0 + sub * 16 + c16;
                int rel = col_g - row_g;
                rel = rel < -64 ? -64 : (rel > 64 ? 64 : rel);
                float x = (S[sub][r] + qp[wave * 16 + row_l][rel + 64]) * 0.125f;
                int mv = mlds[wave][row_l][sub * 16 + c16];
                sv[sub][r] = mv ? -1e30f : x;
            }
        }

        float m_new[4], alpha[4];
#pragma unroll
        for (int r = 0; r < 4; ++r) {
            float rmax = fmaxf(fmaxf(sv[0][r], sv[1][r]), fmaxf(sv[2][r], sv[3][r]));
            rmax = fmaxf(rmax, __shfl_xor(rmax, 1));
            rmax = fmaxf(rmax, __shfl_xor(rmax, 2));
            rmax = fmaxf(rmax, __shfl_xor(rmax, 4));
            rmax = fmaxf(rmax, __shfl_xor(rmax, 8));
            m_new[r] = fmaxf(m_run[r], rmax);
            alpha[r] = __expf(m_run[r] - m_new[r]);
            m_run[r] = m_new[r];
        }
#pragma unroll
        for (int r = 0; r < 4; ++r) {
            float rs = 0.f;
#pragma unroll
            for (int sub = 0; sub < 4; ++sub) {
                float e = __expf(sv[sub][r] - m_new[r]);
                rs += e;
                plds[wave][quad * 4 + r][sub * 16 + c16] = f2bf(e);
            }
            rs += __shfl_xor(rs, 1);
            rs += __shfl_xor(rs, 2);
            rs += __shfl_xor(rs, 4);
            rs += __shfl_xor(rs, 8);
            l_run[r] = l_run[r] * alpha[r] + rs;
#pragma unroll
            for (int d = 0; d < 4; ++d) O[d][r] *= alpha[r];
        }

        bf16x8 pA0 = *reinterpret_cast<bf16x8*>(&plds[wave][c16][quad * 8]);
        bf16x8 pA1 = *reinterpret_cast<bf16x8*>(&plds[wave][c16][32 + quad * 8]);
#pragma unroll
        for (int d = 0; d < 4; ++d) {
            bf16x8 vb0, vb1;
            if (USE_VT) {
                const u16* vtb = (const u16*)vgv + (size_t)b * DIM * SEQ +
                                 (size_t)(d * 16 + c16) * SEQ + k0;
                vb0 = ldg8(vtb + quad * 8);
                vb1 = ldg8(vtb + 32 + quad * 8);
            } else {
                u16 t0[8], t1[8];
                const float* vbase = (const float*)vgv +
                                     ((size_t)b * SEQ + k0) * DIM + d * 16 + c16;
#pragma unroll
                for (int j = 0; j < 8; ++j) {
                    t0[j] = f2bf(vbase[(size_t)(quad * 8 + j) * DIM]);
                    t1[j] = f2bf(vbase[(size_t)(32 + quad * 8 + j) * DIM]);
                }
                vb0 = __builtin_bit_cast(bf16x8, *reinterpret_cast<u32x4*>(t0));
                vb1 = __builtin_bit_cast(bf16x8, *reinterpret_cast<u32x4*>(t1));
            }
            O[d] = __builtin_amdgcn_mfma_f32_16x16x32_bf16(pA0, vb0, O[d], 0, 0, 0);
            O[d] = __builtin_amdgcn_mfma_f32_16x16x32_bf16(pA1, vb1, O[d], 0, 0, 0);
        }
    }

    float* ob = outg + ((size_t)b * SEQ + q0) * DIM;
#pragma unroll
    for (int r = 0; r < 4; ++r) {
        float inv = 1.f / l_run[r];
        int row_l = wave * 16 + quad * 4 + r;
#pragma unroll
        for (int d = 0; d < 4; ++d)
            ob[(size_t)row_l * DIM + d * 16 + c16] = O[d][r] * inv;
    }
}

// ---------------------------------------------------------------------------
extern "C" void kernel_launch(void* const* d_in, const int* in_sizes, int n_in,
                              void* d_out, int out_size, void* d_ws, size_t ws_size,
                              hipStream_t stream) {
    const float* q    = (const float*)d_in[0];
    const float* k    = (const float*)d_in[1];
    const float* v    = (const float*)d_in[2];
    const int*   mask = (const int*)d_in[3];
    const float* pt   = (const float*)d_in[4];
    float* out        = (float*)d_out;

    const size_t vt_bytes = (size_t)BATCH * SEQ * DIM * sizeof(u16);   // 4 MB
    const size_t kb_bytes = (size_t)BATCH * SEQ * DIM * sizeof(u16);   // 4 MB
    const size_t mb_bytes = (size_t)BATCH * SEQ * 16 * sizeof(u64);    // 4 MB
    dim3 grid(SEQ / 64, BATCH);

    if (ws_size >= vt_bytes + kb_bytes + mb_bytes) {
        u16* vt  = (u16*)d_ws;
        u16* kb  = (u16*)((char*)d_ws + vt_bytes);
        u64* mb2 = (u64*)((char*)d_ws + vt_bytes + kb_bytes);
        prep_kernel<<<dim3(4096), 256, 0, stream>>>(k, v, mask, kb, vt, mb2);
        attn_fast4<<<grid, 512, 0, stream>>>(q, kb, vt, mb2, pt, out);
    } else if (ws_size >= vt_bytes) {
        u16* vt = (u16*)d_ws;
        vt_kernel<<<grid, 256, 0, stream>>>(v, vt);
        attn_kernel<true><<<grid, 256, 0, stream>>>(q, k, (const void*)vt, mask, pt, out);
    } else {
        attn_kernel<false><<<grid, 256, 0, stream>>>(q, k, (const void*)v, mask, pt, out);
    }
}

// Round 7
// 286.339 us; speedup vs baseline: 1.2578x; 1.0208x over previous
//
#include <hip/hip_runtime.h>
#include <stdint.h>

#define BATCH 32
#define SEQ   1024
#define DIM   64
#define NKT   (SEQ / 64)

typedef uint8_t  u8;
typedef uint16_t u16;
typedef uint32_t u32;
typedef unsigned long long u64;
typedef __attribute__((ext_vector_type(8))) __bf16 bf16x8;
typedef __attribute__((ext_vector_type(4))) float  f32x4;
typedef __attribute__((ext_vector_type(4))) u32    u32x4;

__device__ __forceinline__ float fexp2(float x) {
#if __has_builtin(__builtin_amdgcn_exp2f)
    return __builtin_amdgcn_exp2f(x);
#else
    return exp2f(x);
#endif
}

__device__ __forceinline__ u16 f2bf(float f) {
    u32 x = __builtin_bit_cast(u32, f);
    x += 0x7FFFu + ((x >> 16) & 1u);   // round-to-nearest-even
    return (u16)(x >> 16);
}

__device__ __forceinline__ bf16x8 cvt8(const float* __restrict__ p) {
    f32x4 a = *reinterpret_cast<const f32x4*>(p);
    f32x4 b = *reinterpret_cast<const f32x4*>(p + 4);
    u16 t[8];
    t[0] = f2bf(a[0]); t[1] = f2bf(a[1]); t[2] = f2bf(a[2]); t[3] = f2bf(a[3]);
    t[4] = f2bf(b[0]); t[5] = f2bf(b[1]); t[6] = f2bf(b[2]); t[7] = f2bf(b[3]);
    return __builtin_bit_cast(bf16x8, *reinterpret_cast<u32x4*>(t));
}

__device__ __forceinline__ bf16x8 cvt8s(const float* __restrict__ p, float s) {
    f32x4 a = *reinterpret_cast<const f32x4*>(p);
    f32x4 b = *reinterpret_cast<const f32x4*>(p + 4);
    u16 t[8];
    t[0] = f2bf(a[0] * s); t[1] = f2bf(a[1] * s); t[2] = f2bf(a[2] * s); t[3] = f2bf(a[3] * s);
    t[4] = f2bf(b[0] * s); t[5] = f2bf(b[1] * s); t[6] = f2bf(b[2] * s); t[7] = f2bf(b[3] * s);
    return __builtin_bit_cast(bf16x8, *reinterpret_cast<u32x4*>(t));
}

__device__ __forceinline__ bf16x8 ldg8(const u16* p) {
    u32x4 u = *reinterpret_cast<const u32x4*>(p);
    return __builtin_bit_cast(bf16x8, u);
}

// ---------------------------------------------------------------------------
// prep8 (8192 blocks x 256):
//  - every thread: 16 ints of mask -> 16 bytes (mb8[i] = mask[i] != 0),
//    fully coalesced 64B-in / 16B-out streaming.
//  - blocks < 512 additionally: K f32 -> bf16 row-major and V f32 -> Vt bf16
//    [B][D][S] (verbatim from the round-4 passing prep).
// ---------------------------------------------------------------------------
__global__ __launch_bounds__(256) void prep8(
    const int* __restrict__ m, const float* __restrict__ kg,
    const float* __restrict__ vg, u8* __restrict__ mb8,
    u16* __restrict__ kb, u16* __restrict__ vtb_) {
    __shared__ u16 tile[64][72];
    const int t = threadIdx.x;

    {   // ---- mask int32 -> byte ------------------------------------------
        size_t i = ((size_t)blockIdx.x * 256 + t) * 16;
        u32x4 a = *reinterpret_cast<const u32x4*>(m + i);
        u32x4 b = *reinterpret_cast<const u32x4*>(m + i + 4);
        u32x4 c = *reinterpret_cast<const u32x4*>(m + i + 8);
        u32x4 d = *reinterpret_cast<const u32x4*>(m + i + 12);
        u32x4 o;
        o[0] = (u32)(a[0] != 0) | ((u32)(a[1] != 0) << 8) |
               ((u32)(a[2] != 0) << 16) | ((u32)(a[3] != 0) << 24);
        o[1] = (u32)(b[0] != 0) | ((u32)(b[1] != 0) << 8) |
               ((u32)(b[2] != 0) << 16) | ((u32)(b[3] != 0) << 24);
        o[2] = (u32)(c[0] != 0) | ((u32)(c[1] != 0) << 8) |
               ((u32)(c[2] != 0) << 16) | ((u32)(c[3] != 0) << 24);
        o[3] = (u32)(d[0] != 0) | ((u32)(d[1] != 0) << 8) |
               ((u32)(d[2] != 0) << 16) | ((u32)(d[3] != 0) << 24);
        *reinterpret_cast<u32x4*>(mb8 + i) = o;
    }

    if (blockIdx.x < 512) {
        const int b  = blockIdx.x >> 4;
        const int k0 = (blockIdx.x & 15) * 64;

        {   // K f32 -> bf16 row-major (64x64 tile)
            int kk = t >> 2;
            int d0 = (t & 3) * 16;
            const float* src = kg + ((size_t)b * SEQ + k0 + kk) * DIM + d0;
            u16 tmp[16];
#pragma unroll
            for (int i = 0; i < 4; ++i) {
                f32x4 a = *reinterpret_cast<const f32x4*>(src + i * 4);
                tmp[i * 4 + 0] = f2bf(a[0]); tmp[i * 4 + 1] = f2bf(a[1]);
                tmp[i * 4 + 2] = f2bf(a[2]); tmp[i * 4 + 3] = f2bf(a[3]);
            }
            u16* dst = kb + ((size_t)b * SEQ + k0 + kk) * DIM + d0;
            *reinterpret_cast<u32x4*>(dst)     = *reinterpret_cast<u32x4*>(tmp);
            *reinterpret_cast<u32x4*>(dst + 8) = *reinterpret_cast<u32x4*>(tmp + 8);
        }
        {   // V tile -> LDS bf16 -> transposed store
            const float* vb = vg + (size_t)b * SEQ * DIM;
            int kk = t >> 2;
            int d0 = (t & 3) * 16;
            const float* src = vb + (size_t)(k0 + kk) * DIM + d0;
            u16 tmp[16];
#pragma unroll
            for (int i = 0; i < 4; ++i) {
                f32x4 a = *reinterpret_cast<const f32x4*>(src + i * 4);
                tmp[i * 4 + 0] = f2bf(a[0]); tmp[i * 4 + 1] = f2bf(a[1]);
                tmp[i * 4 + 2] = f2bf(a[2]); tmp[i * 4 + 3] = f2bf(a[3]);
            }
            *reinterpret_cast<u32x4*>(&tile[kk][d0])     = *reinterpret_cast<u32x4*>(tmp);
            *reinterpret_cast<u32x4*>(&tile[kk][d0 + 8]) = *reinterpret_cast<u32x4*>(tmp + 8);
        }
        __syncthreads();
        u16* vtb = vtb_ + (size_t)b * DIM * SEQ;
#pragma unroll
        for (int i = 0; i < 2; ++i) {
            int d  = t / 8 + i * 32;
            int ks = (t % 8) * 8;
            u16 tmp[8];
#pragma unroll
            for (int j = 0; j < 8; ++j) tmp[j] = tile[ks + j][d];
            *reinterpret_cast<u32x4*>(vtb + (size_t)d * SEQ + k0 + ks) =
                *reinterpret_cast<u32x4*>(tmp);
        }
    }
}

// ---------------------------------------------------------------------------
// attn_fast7: round-2's passing attn_fast2, verbatim, with ONE change:
// mask bitwords replaced by a byte mask staged per-wave into mlds (single
// buffer, per-wave region -> no barrier), prefetched one tile ahead into a
// named u32x4 register.  512 threads = 8 waves (wq = w&3 rows, wk = w>>2
// K-half); flash-merge of the two halves at the end.
// ---------------------------------------------------------------------------
__global__ __launch_bounds__(512, 4) void attn_fast7(
    const float* __restrict__ qg, const u16* __restrict__ kbf,
    const u16* __restrict__ vt, const u8* __restrict__ mb8,
    const float* __restrict__ ptg, float* __restrict__ outg) {
    __shared__ float qp[64][132];        // 33792 B; reused as combine buffer
    __shared__ u16   plds[8][16][72];    // 18432 B, per-wave P tile
    __shared__ u8    mlds[8][16][64];    //  8192 B, per-wave mask byte tile

    const int b    = blockIdx.y;
    const int q0   = blockIdx.x * 64;
    const int tid  = threadIdx.x;
    const int wave = tid >> 6;
    const int lane = tid & 63;
    const int wq   = wave & 3;
    const int wk   = wave >> 2;
    const int quad = lane >> 4;
    const int c16  = lane & 15;

    const float SC = 0.125f * 1.44269504088896340736f;  // 1/8 * log2(e)

    const float* qb = qg + ((size_t)b * SEQ + q0) * DIM;

    // Q A-fragments, pre-scaled (exp2 space)
    const bf16x8 qA0 = cvt8s(qb + (size_t)(wq * 16 + c16) * DIM + quad * 8, SC);
    const bf16x8 qA1 = cvt8s(qb + (size_t)(wq * 16 + c16) * DIM + 32 + quad * 8, SC);

    // qp[64][129] = (SC*Q)(64x64) . pos_table^T ; jt tiles split across wk
    {
        const int jt0 = wk ? 5 : 0, jt1 = wk ? 9 : 5;
        for (int jt = jt0; jt < jt1; ++jt) {
            int j0 = jt * 16;
            int jr = min(j0 + c16, 128);
            bf16x8 b0 = cvt8(ptg + (size_t)jr * DIM + quad * 8);
            bf16x8 b1 = cvt8(ptg + (size_t)jr * DIM + 32 + quad * 8);
            f32x4 acc = {0.f, 0.f, 0.f, 0.f};
            acc = __builtin_amdgcn_mfma_f32_16x16x32_bf16(qA0, b0, acc, 0, 0, 0);
            acc = __builtin_amdgcn_mfma_f32_16x16x32_bf16(qA1, b1, acc, 0, 0, 0);
            int jcol = j0 + c16;
            if (jcol <= 128) {
#pragma unroll
                for (int r = 0; r < 4; ++r)
                    qp[wq * 16 + quad * 4 + r][jcol] = acc[r];
            }
        }
    }
    __syncthreads();   // qp complete (both halves)

    const u16* kb_base  = kbf + (size_t)b * SEQ * DIM;
    const u16* vtb_base = vt  + (size_t)b * DIM * SEQ;

    // mask byte source for this lane: row q0 + wq*16 + (lane>>2), 16B chunk (lane&3)
    const u8* m8 = mb8 + (size_t)b * SEQ * SEQ +
                   (size_t)(q0 + wq * 16 + (lane >> 2)) * SEQ + (lane & 3) * 16;

    // prefetch first tile's mask bytes (tile kt = wk*8)
    u32x4 mcur = *reinterpret_cast<const u32x4*>(m8 + (size_t)(wk * 8) * 64);
    u32x4 mnext;

    float m_run[4], l_run[4];
    f32x4 O[4];
#pragma unroll
    for (int r = 0; r < 4; ++r) { m_run[r] = -1e30f; l_run[r] = 0.f; }
#pragma unroll
    for (int d = 0; d < 4; ++d) O[d] = f32x4{0.f, 0.f, 0.f, 0.f};

#pragma unroll
    for (int gg = 0; gg < 2; ++gg) {
#pragma unroll 1
        for (int t = 0; t < 4; ++t) {
            const int kt = wk * 8 + gg * 4 + t;
            const int k0 = kt * 64;

            // stage this tile's mask bytes (per-wave LDS, in-order, no barrier)
            *reinterpret_cast<u32x4*>(&mlds[wave][lane >> 2][(lane & 3) * 16]) = mcur;
            // prefetch next tile's bytes (wrapped index keeps it in-bounds)
            mnext = *reinterpret_cast<const u32x4*>(m8 + (size_t)((kt + 1) & 15) * 64);

            // --- S = (SC*Q) . K^T (direct bf16 fragment loads) -------------
            f32x4 S[4];
            __builtin_amdgcn_s_setprio(1);
#pragma unroll
            for (int sub = 0; sub < 4; ++sub) {
                const u16* kr = kb_base + (size_t)(k0 + sub * 16 + c16) * DIM;
                bf16x8 kf0 = ldg8(kr + quad * 8);
                bf16x8 kf1 = ldg8(kr + 32 + quad * 8);
                f32x4 acc = {0.f, 0.f, 0.f, 0.f};
                acc = __builtin_amdgcn_mfma_f32_16x16x32_bf16(qA0, kf0, acc, 0, 0, 0);
                acc = __builtin_amdgcn_mfma_f32_16x16x32_bf16(qA1, kf1, acc, 0, 0, 0);
                S[sub] = acc;
            }
            __builtin_amdgcn_s_setprio(0);

            // --- logits: + qp gather, mask byte select ---------------------
            float sv[4][4];
#pragma unroll
            for (int r = 0; r < 4; ++r) {
                const int row_l = quad * 4 + r;
                const int row_g = q0 + wq * 16 + row_l;
#pragma unroll
                for (int sub = 0; sub < 4; ++sub) {
                    int col_g = k0 + sub * 16 + c16;
                    int rel = col_g - row_g;
                    rel = rel < -64 ? -64 : (rel > 64 ? 64 : rel);
                    float x = S[sub][r] + qp[wq * 16 + row_l][rel + 64];
                    u8 mv = mlds[wave][row_l][sub * 16 + c16];
                    sv[sub][r] = mv ? -1e30f : x;
                }
            }

            // --- online softmax (exp2 space), defer-rescale when flat ------
            float m_new[4];
            bool need = false;
#pragma unroll
            for (int r = 0; r < 4; ++r) {
                float rmax = fmaxf(fmaxf(sv[0][r], sv[1][r]), fmaxf(sv[2][r], sv[3][r]));
                rmax = fmaxf(rmax, __shfl_xor(rmax, 1));
                rmax = fmaxf(rmax, __shfl_xor(rmax, 2));
                rmax = fmaxf(rmax, __shfl_xor(rmax, 4));
                rmax = fmaxf(rmax, __shfl_xor(rmax, 8));
                m_new[r] = fmaxf(m_run[r], rmax);
                need |= (m_new[r] > m_run[r]);
            }
            if (__any(need)) {
#pragma unroll
                for (int r = 0; r < 4; ++r) {
                    float alpha = fexp2(m_run[r] - m_new[r]);
                    l_run[r] *= alpha;
#pragma unroll
                    for (int d = 0; d < 4; ++d) O[d][r] *= alpha;
                }
            }
#pragma unroll
            for (int r = 0; r < 4; ++r) {
                m_run[r] = m_new[r];
                float rs = 0.f;
#pragma unroll
                for (int sub = 0; sub < 4; ++sub) {
                    float e = fexp2(sv[sub][r] - m_new[r]);  // masked -> 0
                    rs += e;
                    plds[wave][quad * 4 + r][sub * 16 + c16] = f2bf(e);
                }
                rs += __shfl_xor(rs, 1);
                rs += __shfl_xor(rs, 2);
                rs += __shfl_xor(rs, 4);
                rs += __shfl_xor(rs, 8);
                l_run[r] += rs;
            }

            // --- P (A-layout from per-wave LDS) and PV accumulate ----------
            bf16x8 pA0 = *reinterpret_cast<bf16x8*>(&plds[wave][c16][quad * 8]);
            bf16x8 pA1 = *reinterpret_cast<bf16x8*>(&plds[wave][c16][32 + quad * 8]);
            __builtin_amdgcn_s_setprio(1);
#pragma unroll
            for (int d = 0; d < 4; ++d) {
                const u16* vr = vtb_base + (size_t)(d * 16 + c16) * SEQ + k0;
                bf16x8 vf0 = ldg8(vr + quad * 8);
                bf16x8 vf1 = ldg8(vr + 32 + quad * 8);
                O[d] = __builtin_amdgcn_mfma_f32_16x16x32_bf16(pA0, vf0, O[d], 0, 0, 0);
                O[d] = __builtin_amdgcn_mfma_f32_16x16x32_bf16(pA1, vf1, O[d], 0, 0, 0);
            }
            __builtin_amdgcn_s_setprio(0);

            mcur = mnext;
        }
    }

    // --- flash-merge the two K-halves (combine buffer overlays dead qp) ----
    __syncthreads();   // everyone done reading qp
    float* cmb = &qp[0][0];
    const int cbase = (wq * 64 + lane) * 24;
    if (wk == 1) {
#pragma unroll
        for (int r = 0; r < 4; ++r) {
            cmb[cbase + r]     = m_run[r];
            cmb[cbase + 4 + r] = l_run[r];
        }
#pragma unroll
        for (int d = 0; d < 4; ++d)
#pragma unroll
            for (int r = 0; r < 4; ++r)
                cmb[cbase + 8 + d * 4 + r] = O[d][r];
    }
    __syncthreads();
    if (wk == 0) {
        float* ob = outg + ((size_t)b * SEQ + q0) * DIM;
#pragma unroll
        for (int r = 0; r < 4; ++r) {
            float m1 = cmb[cbase + r];
            float l1 = cmb[cbase + 4 + r];
            float mm = fmaxf(m_run[r], m1);
            float a0 = fexp2(m_run[r] - mm);
            float a1 = fexp2(m1 - mm);
            float inv = 1.f / (l_run[r] * a0 + l1 * a1);
            int row_l = wq * 16 + quad * 4 + r;
#pragma unroll
            for (int d = 0; d < 4; ++d) {
                float o = O[d][r] * a0 + cmb[cbase + 8 + d * 4 + r] * a1;
                ob[(size_t)row_l * DIM + d * 16 + c16] = o * inv;
            }
        }
    }
}

// ---------------------------------------------------------------------------
// Fallback kernels (workspace too small for fast path).
// ---------------------------------------------------------------------------
__global__ __launch_bounds__(256) void vt_kernel(const float* __restrict__ v,
                                                 u16* __restrict__ vt) {
    __shared__ u16 tile[64][72];
    const int b  = blockIdx.y;
    const int k0 = blockIdx.x * 64;
    const int t  = threadIdx.x;
    const float* vb  = v  + (size_t)b * SEQ * DIM;
    u16*         vtb = vt + (size_t)b * DIM * SEQ;

    {
        int kk = t >> 2;
        int d0 = (t & 3) * 16;
        const float* src = vb + (size_t)(k0 + kk) * DIM + d0;
        u16 tmp[16];
#pragma unroll
        for (int i = 0; i < 4; ++i) {
            f32x4 a = *reinterpret_cast<const f32x4*>(src + i * 4);
            tmp[i * 4 + 0] = f2bf(a[0]); tmp[i * 4 + 1] = f2bf(a[1]);
            tmp[i * 4 + 2] = f2bf(a[2]); tmp[i * 4 + 3] = f2bf(a[3]);
        }
        *reinterpret_cast<u32x4*>(&tile[kk][d0])     = *reinterpret_cast<u32x4*>(tmp);
        *reinterpret_cast<u32x4*>(&tile[kk][d0 + 8]) = *reinterpret_cast<u32x4*>(tmp + 8);
    }
    __syncthreads();
#pragma unroll
    for (int i = 0; i < 2; ++i) {
        int d  = t / 8 + i * 32;
        int ks = (t % 8) * 8;
        u16 tmp[8];
#pragma unroll
        for (int j = 0; j < 8; ++j) tmp[j] = tile[ks + j][d];
        *reinterpret_cast<u32x4*>(vtb + (size_t)d * SEQ + k0 + ks) =
            *reinterpret_cast<u32x4*>(tmp);
    }
}

template <bool USE_VT>
__global__ __launch_bounds__(256, 2) void attn_kernel(
    const float* __restrict__ qg, const float* __restrict__ kg,
    const void* __restrict__ vgv, const int* __restrict__ maskg,
    const float* __restrict__ ptg, float* __restrict__ outg) {
    __shared__ float qp[64][132];
    __shared__ int   mlds[4][16][68];
    __shared__ u16   plds[4][16][72];

    const int b    = blockIdx.y;
    const int q0   = blockIdx.x * 64;
    const int tid  = threadIdx.x;
    const int wave = tid >> 6;
    const int lane = tid & 63;
    const int quad = lane >> 4;
    const int c16  = lane & 15;

    const float* qb = qg + ((size_t)b * SEQ + q0) * DIM;
    const float* kb = kg + (size_t)b * SEQ * DIM;
    const int*   mb = maskg + ((size_t)b * SEQ + q0) * SEQ;

    const bf16x8 qA0 = cvt8(qb + (size_t)(wave * 16 + c16) * DIM + quad * 8);
    const bf16x8 qA1 = cvt8(qb + (size_t)(wave * 16 + c16) * DIM + 32 + quad * 8);

    for (int jt = 0; jt < 9; ++jt) {
        int j0 = jt * 16;
        int jr = min(j0 + c16, 128);
        bf16x8 b0 = cvt8(ptg + (size_t)jr * DIM + quad * 8);
        bf16x8 b1 = cvt8(ptg + (size_t)jr * DIM + 32 + quad * 8);
        f32x4 acc = {0.f, 0.f, 0.f, 0.f};
        acc = __builtin_amdgcn_mfma_f32_16x16x32_bf16(qA0, b0, acc, 0, 0, 0);
        acc = __builtin_amdgcn_mfma_f32_16x16x32_bf16(qA1, b1, acc, 0, 0, 0);
        int jcol = j0 + c16;
        if (jcol <= 128) {
#pragma unroll
            for (int r = 0; r < 4; ++r)
                qp[wave * 16 + quad * 4 + r][jcol] = acc[r];
        }
    }

    float m_run[4], l_run[4];
    f32x4 O[4];
#pragma unroll
    for (int r = 0; r < 4; ++r) { m_run[r] = -1e30f; l_run[r] = 0.f; }
#pragma unroll
    for (int d = 0; d < 4; ++d) O[d] = f32x4{0.f, 0.f, 0.f, 0.f};

#pragma unroll 1
    for (int kt = 0; kt < NKT; ++kt) {
        const int k0 = kt * 64;
        {
            int row_l = lane >> 2;
            const int* mrow = mb + (size_t)(wave * 16 + row_l) * SEQ + k0;
#pragma unroll
            for (int i = 0; i < 4; ++i) {
                int seg = (lane & 3) + i * 4;
                *reinterpret_cast<u32x4*>(&mlds[wave][row_l][seg * 4]) =
                    *reinterpret_cast<const u32x4*>(mrow + seg * 4);
            }
        }

        f32x4 S[4];
#pragma unroll
        for (int sub = 0; sub < 4; ++sub) {
            const float* kr = kb + (size_t)(k0 + sub * 16 + c16) * DIM;
            bf16x8 kb0 = cvt8(kr + quad * 8);
            bf16x8 kb1 = cvt8(kr + 32 + quad * 8);
            f32x4 acc = {0.f, 0.f, 0.f, 0.f};
            acc = __builtin_amdgcn_mfma_f32_16x16x32_bf16(qA0, kb0, acc, 0, 0, 0);
            acc = __builtin_amdgcn_mfma_f32_16x16x32_bf16(qA1, kb1, acc, 0, 0, 0);
            S[sub] = acc;
        }

        float sv[4][4];
#pragma unroll
        for (int sub = 0; sub < 4; ++sub) {
#pragma unroll
            for (int r = 0; r < 4; ++r) {
                int row_l = quad * 4 + r;
                int row_g = q0 + wave * 16 + row_l;
                int col_g = k0 + sub * 16 + c16;
                int rel = col_g - row_g;
                rel = rel < -64 ? -64 : (rel > 64 ? 64 : rel);
                float x = (S[sub][r] + qp[wave * 16 + row_l][rel + 64]) * 0.125f;
                int mv = mlds[wave][row_l][sub * 16 + c16];
                sv[sub][r] = mv ? -1e30f : x;
            }
        }

        float m_new[4], alpha[4];
#pragma unroll
        for (int r = 0; r < 4; ++r) {
            float rmax = fmaxf(fmaxf(sv[0][r], sv[1][r]), fmaxf(sv[2][r], sv[3][r]));
            rmax = fmaxf(rmax, __shfl_xor(rmax, 1));
            rmax = fmaxf(rmax, __shfl_xor(rmax, 2));
            rmax = fmaxf(rmax, __shfl_xor(rmax, 4));
            rmax = fmaxf(rmax, __shfl_xor(rmax, 8));
            m_new[r] = fmaxf(m_run[r], rmax);
            alpha[r] = __expf(m_run[r] - m_new[r]);
            m_run[r] = m_new[r];
        }
#pragma unroll
        for (int r = 0; r < 4; ++r) {
            float rs = 0.f;
#pragma unroll
            for (int sub = 0; sub < 4; ++sub) {
                float e = __expf(sv[sub][r] - m_new[r]);
                rs += e;
                plds[wave][quad * 4 + r][sub * 16 + c16] = f2bf(e);
            }
            rs += __shfl_xor(rs, 1);
            rs += __shfl_xor(rs, 2);
            rs += __shfl_xor(rs, 4);
            rs += __shfl_xor(rs, 8);
            l_run[r] = l_run[r] * alpha[r] + rs;
#pragma unroll
            for (int d = 0; d < 4; ++d) O[d][r] *= alpha[r];
        }

        bf16x8 pA0 = *reinterpret_cast<bf16x8*>(&plds[wave][c16][quad * 8]);
        bf16x8 pA1 = *reinterpret_cast<bf16x8*>(&plds[wave][c16][32 + quad * 8]);
#pragma unroll
        for (int d = 0; d < 4; ++d) {
            bf16x8 vb0, vb1;
            if (USE_VT) {
                const u16* vtb = (const u16*)vgv + (size_t)b * DIM * SEQ +
                                 (size_t)(d * 16 + c16) * SEQ + k0;
                vb0 = ldg8(vtb + quad * 8);
                vb1 = ldg8(vtb + 32 + quad * 8);
            } else {
                u16 t0[8], t1[8];
                const float* vbase = (const float*)vgv +
                                     ((size_t)b * SEQ + k0) * DIM + d * 16 + c16;
#pragma unroll
                for (int jj = 0; jj < 8; ++jj) {
                    t0[jj] = f2bf(vbase[(size_t)(quad * 8 + jj) * DIM]);
                    t1[jj] = f2bf(vbase[(size_t)(32 + quad * 8 + jj) * DIM]);
                }
                vb0 = __builtin_bit_cast(bf16x8, *reinterpret_cast<u32x4*>(t0));
                vb1 = __builtin_bit_cast(bf16x8, *reinterpret_cast<u32x4*>(t1));
            }
            O[d] = __builtin_amdgcn_mfma_f32_16x16x32_bf16(pA0, vb0, O[d], 0, 0, 0);
            O[d] = __builtin_amdgcn_mfma_f32_16x16x32_bf16(pA1, vb1, O[d], 0, 0, 0);
        }
    }

    float* ob = outg + ((size_t)b * SEQ + q0) * DIM;
#pragma unroll
    for (int r = 0; r < 4; ++r) {
        float inv = 1.f / l_run[r];
        int row_l = wave * 16 + quad * 4 + r;
#pragma unroll
        for (int d = 0; d < 4; ++d)
            ob[(size_t)row_l * DIM + d * 16 + c16] = O[d][r] * inv;
    }
}

// ---------------------------------------------------------------------------
extern "C" void kernel_launch(void* const* d_in, const int* in_sizes, int n_in,
                              void* d_out, int out_size, void* d_ws, size_t ws_size,
                              hipStream_t stream) {
    const float* q    = (const float*)d_in[0];
    const float* k    = (const float*)d_in[1];
    const float* v    = (const float*)d_in[2];
    const int*   mask = (const int*)d_in[3];
    const float* pt   = (const float*)d_in[4];
    float* out        = (float*)d_out;

    const size_t vt_bytes = (size_t)BATCH * SEQ * DIM * sizeof(u16);   //  4 MB
    const size_t kb_bytes = (size_t)BATCH * SEQ * DIM * sizeof(u16);   //  4 MB
    const size_t m8_bytes = (size_t)BATCH * SEQ * SEQ;                 // 32 MB
    dim3 grid(SEQ / 64, BATCH);

    if (ws_size >= vt_bytes + kb_bytes + m8_bytes) {
        u16* vt  = (u16*)d_ws;
        u16* kb  = (u16*)((char*)d_ws + vt_bytes);
        u8*  mb8 = (u8*)((char*)d_ws + vt_bytes + kb_bytes);
        prep8<<<dim3(8192), 256, 0, stream>>>(mask, k, v, mb8, kb, vt);
        attn_fast7<<<grid, 512, 0, stream>>>(q, kb, vt, mb8, pt, out);
    } else if (ws_size >= vt_bytes) {
        u16* vt = (u16*)d_ws;
        vt_kernel<<<grid, 256, 0, stream>>>(v, vt);
        attn_kernel<true><<<grid, 256, 0, stream>>>(q, k, (const void*)vt, mask, pt, out);
    } else {
        attn_kernel<false><<<grid, 256, 0, stream>>>(q, k, (const void*)v, mask, pt, out);
    }
}

// Round 8
// 268.112 us; speedup vs baseline: 1.3433x; 1.0680x over previous
//
#include <hip/hip_runtime.h>
#include <stdint.h>

#define BATCH 32
#define SEQ   1024
#define DIM   64
#define NKT   (SEQ / 64)

typedef uint8_t  u8;
typedef uint16_t u16;
typedef uint32_t u32;
typedef unsigned long long u64;
typedef __attribute__((ext_vector_type(8))) __bf16 bf16x8;
typedef __attribute__((ext_vector_type(4))) float  f32x4;
typedef __attribute__((ext_vector_type(4))) u32    u32x4;

__device__ __forceinline__ float fexp2(float x) {
#if __has_builtin(__builtin_amdgcn_exp2f)
    return __builtin_amdgcn_exp2f(x);
#else
    return exp2f(x);
#endif
}

__device__ __forceinline__ u16 f2bf(float f) {
    u32 x = __builtin_bit_cast(u32, f);
    x += 0x7FFFu + ((x >> 16) & 1u);   // round-to-nearest-even
    return (u16)(x >> 16);
}

__device__ __forceinline__ bf16x8 cvt8(const float* __restrict__ p) {
    f32x4 a = *reinterpret_cast<const f32x4*>(p);
    f32x4 b = *reinterpret_cast<const f32x4*>(p + 4);
    u16 t[8];
    t[0] = f2bf(a[0]); t[1] = f2bf(a[1]); t[2] = f2bf(a[2]); t[3] = f2bf(a[3]);
    t[4] = f2bf(b[0]); t[5] = f2bf(b[1]); t[6] = f2bf(b[2]); t[7] = f2bf(b[3]);
    return __builtin_bit_cast(bf16x8, *reinterpret_cast<u32x4*>(t));
}

__device__ __forceinline__ bf16x8 cvt8s(const float* __restrict__ p, float s) {
    f32x4 a = *reinterpret_cast<const f32x4*>(p);
    f32x4 b = *reinterpret_cast<const f32x4*>(p + 4);
    u16 t[8];
    t[0] = f2bf(a[0] * s); t[1] = f2bf(a[1] * s); t[2] = f2bf(a[2] * s); t[3] = f2bf(a[3] * s);
    t[4] = f2bf(b[0] * s); t[5] = f2bf(b[1] * s); t[6] = f2bf(b[2] * s); t[7] = f2bf(b[3] * s);
    return __builtin_bit_cast(bf16x8, *reinterpret_cast<u32x4*>(t));
}

__device__ __forceinline__ bf16x8 ldg8(const u16* p) {
    u32x4 u = *reinterpret_cast<const u32x4*>(p);
    return __builtin_bit_cast(bf16x8, u);
}

// pack 4 ints' nonzero-ness into 4 bytes of a u32
__device__ __forceinline__ u32 pack4(u32x4 a) {
    return (u32)(a[0] != 0) | ((u32)(a[1] != 0) << 8) |
           ((u32)(a[2] != 0) << 16) | ((u32)(a[3] != 0) << 24);
}

// ---------------------------------------------------------------------------
// prep_kv (512 blocks): K f32 -> bf16 row-major; V f32 -> Vt bf16 [B][D][S].
// (~24 MB traffic total; no mask prepass — attn reads the int mask directly.)
// ---------------------------------------------------------------------------
__global__ __launch_bounds__(256) void prep_kv(
    const float* __restrict__ kg, const float* __restrict__ vg,
    u16* __restrict__ kb, u16* __restrict__ vtb_) {
    __shared__ u16 tile[64][72];
    const int t  = threadIdx.x;
    const int b  = blockIdx.x >> 4;
    const int k0 = (blockIdx.x & 15) * 64;

    {   // K f32 -> bf16 row-major (64x64 tile)
        int kk = t >> 2;
        int d0 = (t & 3) * 16;
        const float* src = kg + ((size_t)b * SEQ + k0 + kk) * DIM + d0;
        u16 tmp[16];
#pragma unroll
        for (int i = 0; i < 4; ++i) {
            f32x4 a = *reinterpret_cast<const f32x4*>(src + i * 4);
            tmp[i * 4 + 0] = f2bf(a[0]); tmp[i * 4 + 1] = f2bf(a[1]);
            tmp[i * 4 + 2] = f2bf(a[2]); tmp[i * 4 + 3] = f2bf(a[3]);
        }
        u16* dst = kb + ((size_t)b * SEQ + k0 + kk) * DIM + d0;
        *reinterpret_cast<u32x4*>(dst)     = *reinterpret_cast<u32x4*>(tmp);
        *reinterpret_cast<u32x4*>(dst + 8) = *reinterpret_cast<u32x4*>(tmp + 8);
    }
    {   // V tile -> LDS bf16 -> transposed store
        const float* vb = vg + (size_t)b * SEQ * DIM;
        int kk = t >> 2;
        int d0 = (t & 3) * 16;
        const float* src = vb + (size_t)(k0 + kk) * DIM + d0;
        u16 tmp[16];
#pragma unroll
        for (int i = 0; i < 4; ++i) {
            f32x4 a = *reinterpret_cast<const f32x4*>(src + i * 4);
            tmp[i * 4 + 0] = f2bf(a[0]); tmp[i * 4 + 1] = f2bf(a[1]);
            tmp[i * 4 + 2] = f2bf(a[2]); tmp[i * 4 + 3] = f2bf(a[3]);
        }
        *reinterpret_cast<u32x4*>(&tile[kk][d0])     = *reinterpret_cast<u32x4*>(tmp);
        *reinterpret_cast<u32x4*>(&tile[kk][d0 + 8]) = *reinterpret_cast<u32x4*>(tmp + 8);
    }
    __syncthreads();
    u16* vtb = vtb_ + (size_t)b * DIM * SEQ;
#pragma unroll
    for (int i = 0; i < 2; ++i) {
        int d  = t / 8 + i * 32;
        int ks = (t % 8) * 8;
        u16 tmp[8];
#pragma unroll
        for (int j = 0; j < 8; ++j) tmp[j] = tile[ks + j][d];
        *reinterpret_cast<u32x4*>(vtb + (size_t)d * SEQ + k0 + ks) =
            *reinterpret_cast<u32x4*>(tmp);
    }
}

// ---------------------------------------------------------------------------
// attn_fast8: r7 structure (8 waves split-K) with NO-MAX softmax.
// Logits are bounded (|s| <~ 17 in exp2 space), so e = exp2(s) raw, l summed
// lane-locally (one reduce at the end), O unscaled, merge = plain adds.
// Mask: read int32 directly (4 x u32x4/lane/tile, prefetched one tile ahead
// in named regs), packed to bytes in-register, staged per-wave in mlds.
// ---------------------------------------------------------------------------
__global__ __launch_bounds__(512, 4) void attn_fast8(
    const float* __restrict__ qg, const u16* __restrict__ kbf,
    const u16* __restrict__ vt, const int* __restrict__ maskg,
    const float* __restrict__ ptg, float* __restrict__ outg) {
    __shared__ float qp[64][132];        // 33792 B; reused as combine buffer
    __shared__ u16   plds[8][16][72];    // 18432 B, per-wave P tile
    __shared__ u8    mlds[8][16][64];    //  8192 B, per-wave mask byte tile

    const int b    = blockIdx.y;
    const int q0   = blockIdx.x * 64;
    const int tid  = threadIdx.x;
    const int wave = tid >> 6;
    const int lane = tid & 63;
    const int wq   = wave & 3;
    const int wk   = wave >> 2;
    const int quad = lane >> 4;
    const int c16  = lane & 15;

    const float SC = 0.125f * 1.44269504088896340736f;  // 1/8 * log2(e)

    const float* qb = qg + ((size_t)b * SEQ + q0) * DIM;

    // Q A-fragments, pre-scaled (exp2 space)
    const bf16x8 qA0 = cvt8s(qb + (size_t)(wq * 16 + c16) * DIM + quad * 8, SC);
    const bf16x8 qA1 = cvt8s(qb + (size_t)(wq * 16 + c16) * DIM + 32 + quad * 8, SC);

    // qp[64][129] = (SC*Q)(64x64) . pos_table^T ; jt tiles split across wk
    {
        const int jt0 = wk ? 5 : 0, jt1 = wk ? 9 : 5;
        for (int jt = jt0; jt < jt1; ++jt) {
            int j0 = jt * 16;
            int jr = min(j0 + c16, 128);
            bf16x8 b0 = cvt8(ptg + (size_t)jr * DIM + quad * 8);
            bf16x8 b1 = cvt8(ptg + (size_t)jr * DIM + 32 + quad * 8);
            f32x4 acc = {0.f, 0.f, 0.f, 0.f};
            acc = __builtin_amdgcn_mfma_f32_16x16x32_bf16(qA0, b0, acc, 0, 0, 0);
            acc = __builtin_amdgcn_mfma_f32_16x16x32_bf16(qA1, b1, acc, 0, 0, 0);
            int jcol = j0 + c16;
            if (jcol <= 128) {
#pragma unroll
                for (int r = 0; r < 4; ++r)
                    qp[wq * 16 + quad * 4 + r][jcol] = acc[r];
            }
        }
    }
    __syncthreads();   // qp complete (both halves)

    const u16* kb_base  = kbf + (size_t)b * SEQ * DIM;
    const u16* vtb_base = vt  + (size_t)b * DIM * SEQ;

    // int-mask source for this lane: row q0+wq*16+(lane>>2), 16-int chunk (lane&3)
    const int* mrow = maskg + ((size_t)b * SEQ + q0 + wq * 16 + (lane >> 2)) * SEQ +
                      (lane & 3) * 16;

    // prefetch first tile's mask ints (tile kt = wk*8): 4 x u32x4 in flight
    u32x4 ma, mbv, mc, md;
    {
        const int* p = mrow + (size_t)(wk * 8) * 64;
        ma  = *reinterpret_cast<const u32x4*>(p);
        mbv = *reinterpret_cast<const u32x4*>(p + 4);
        mc  = *reinterpret_cast<const u32x4*>(p + 8);
        md  = *reinterpret_cast<const u32x4*>(p + 12);
    }

    float l_part[4];
    f32x4 O[4];
#pragma unroll
    for (int r = 0; r < 4; ++r) l_part[r] = 0.f;
#pragma unroll
    for (int d = 0; d < 4; ++d) O[d] = f32x4{0.f, 0.f, 0.f, 0.f};

#pragma unroll
    for (int gg = 0; gg < 2; ++gg) {
#pragma unroll 1
        for (int t = 0; t < 4; ++t) {
            const int kt = wk * 8 + gg * 4 + t;
            const int k0 = kt * 64;

            // pack current tile's mask ints -> bytes, stage to per-wave LDS
            {
                u32x4 pk;
                pk[0] = pack4(ma); pk[1] = pack4(mbv);
                pk[2] = pack4(mc); pk[3] = pack4(md);
                *reinterpret_cast<u32x4*>(&mlds[wave][lane >> 2][(lane & 3) * 16]) = pk;
            }
            // prefetch next tile's ints (wrapped index keeps it in-bounds)
            {
                const int* p = mrow + (size_t)((kt + 1) & 15) * 64;
                ma  = *reinterpret_cast<const u32x4*>(p);
                mbv = *reinterpret_cast<const u32x4*>(p + 4);
                mc  = *reinterpret_cast<const u32x4*>(p + 8);
                md  = *reinterpret_cast<const u32x4*>(p + 12);
            }

            // --- S = (SC*Q) . K^T (direct bf16 fragment loads) -------------
            f32x4 S[4];
            __builtin_amdgcn_s_setprio(1);
#pragma unroll
            for (int sub = 0; sub < 4; ++sub) {
                const u16* kr = kb_base + (size_t)(k0 + sub * 16 + c16) * DIM;
                bf16x8 kf0 = ldg8(kr + quad * 8);
                bf16x8 kf1 = ldg8(kr + 32 + quad * 8);
                f32x4 acc = {0.f, 0.f, 0.f, 0.f};
                acc = __builtin_amdgcn_mfma_f32_16x16x32_bf16(qA0, kf0, acc, 0, 0, 0);
                acc = __builtin_amdgcn_mfma_f32_16x16x32_bf16(qA1, kf1, acc, 0, 0, 0);
                S[sub] = acc;
            }
            __builtin_amdgcn_s_setprio(0);

            // --- logits -> e = exp2(s) raw; lane-local l; P to LDS ---------
#pragma unroll
            for (int r = 0; r < 4; ++r) {
                const int row_l = quad * 4 + r;
                const int row_g = q0 + wq * 16 + row_l;
                float rs = 0.f;
#pragma unroll
                for (int sub = 0; sub < 4; ++sub) {
                    int col_g = k0 + sub * 16 + c16;
                    int rel = col_g - row_g;
                    rel = rel < -64 ? -64 : (rel > 64 ? 64 : rel);
                    float x = S[sub][r] + qp[wq * 16 + row_l][rel + 64];
                    u8 mv = mlds[wave][row_l][sub * 16 + c16];
                    float e = mv ? 0.f : fexp2(x);   // bounded: |x| <~ 17
                    rs += e;
                    plds[wave][row_l][sub * 16 + c16] = f2bf(e);
                }
                l_part[r] += rs;
            }

            // --- P (A-layout from per-wave LDS) and PV accumulate ----------
            bf16x8 pA0 = *reinterpret_cast<bf16x8*>(&plds[wave][c16][quad * 8]);
            bf16x8 pA1 = *reinterpret_cast<bf16x8*>(&plds[wave][c16][32 + quad * 8]);
            __builtin_amdgcn_s_setprio(1);
#pragma unroll
            for (int d = 0; d < 4; ++d) {
                const u16* vr = vtb_base + (size_t)(d * 16 + c16) * SEQ + k0;
                bf16x8 vf0 = ldg8(vr + quad * 8);
                bf16x8 vf1 = ldg8(vr + 32 + quad * 8);
                O[d] = __builtin_amdgcn_mfma_f32_16x16x32_bf16(pA0, vf0, O[d], 0, 0, 0);
                O[d] = __builtin_amdgcn_mfma_f32_16x16x32_bf16(pA1, vf1, O[d], 0, 0, 0);
            }
            __builtin_amdgcn_s_setprio(0);
        }
    }

    // --- one l reduce at the end (was per-iteration before) ----------------
    float l_run[4];
#pragma unroll
    for (int r = 0; r < 4; ++r) {
        float rs = l_part[r];
        rs += __shfl_xor(rs, 1);
        rs += __shfl_xor(rs, 2);
        rs += __shfl_xor(rs, 4);
        rs += __shfl_xor(rs, 8);
        l_run[r] = rs;
    }

    // --- merge the two K-halves: plain adds (same shift = 0 on both) -------
    __syncthreads();   // everyone done reading qp
    float* cmb = &qp[0][0];
    const int cbase = (wq * 64 + lane) * 24;
    if (wk == 1) {
#pragma unroll
        for (int r = 0; r < 4; ++r) cmb[cbase + r] = l_run[r];
#pragma unroll
        for (int d = 0; d < 4; ++d)
#pragma unroll
            for (int r = 0; r < 4; ++r)
                cmb[cbase + 4 + d * 4 + r] = O[d][r];
    }
    __syncthreads();
    if (wk == 0) {
        float* ob = outg + ((size_t)b * SEQ + q0) * DIM;
#pragma unroll
        for (int r = 0; r < 4; ++r) {
            float inv = 1.f / (l_run[r] + cmb[cbase + r]);
            int row_l = wq * 16 + quad * 4 + r;
#pragma unroll
            for (int d = 0; d < 4; ++d) {
                float o = O[d][r] + cmb[cbase + 4 + d * 4 + r];
                ob[(size_t)row_l * DIM + d * 16 + c16] = o * inv;
            }
        }
    }
}

// ---------------------------------------------------------------------------
// Fallback kernels (workspace too small for fast path).
// ---------------------------------------------------------------------------
__global__ __launch_bounds__(256) void vt_kernel(const float* __restrict__ v,
                                                 u16* __restrict__ vt) {
    __shared__ u16 tile[64][72];
    const int b  = blockIdx.y;
    const int k0 = blockIdx.x * 64;
    const int t  = threadIdx.x;
    const float* vb  = v  + (size_t)b * SEQ * DIM;
    u16*         vtb = vt + (size_t)b * DIM * SEQ;

    {
        int kk = t >> 2;
        int d0 = (t & 3) * 16;
        const float* src = vb + (size_t)(k0 + kk) * DIM + d0;
        u16 tmp[16];
#pragma unroll
        for (int i = 0; i < 4; ++i) {
            f32x4 a = *reinterpret_cast<const f32x4*>(src + i * 4);
            tmp[i * 4 + 0] = f2bf(a[0]); tmp[i * 4 + 1] = f2bf(a[1]);
            tmp[i * 4 + 2] = f2bf(a[2]); tmp[i * 4 + 3] = f2bf(a[3]);
        }
        *reinterpret_cast<u32x4*>(&tile[kk][d0])     = *reinterpret_cast<u32x4*>(tmp);
        *reinterpret_cast<u32x4*>(&tile[kk][d0 + 8]) = *reinterpret_cast<u32x4*>(tmp + 8);
    }
    __syncthreads();
#pragma unroll
    for (int i = 0; i < 2; ++i) {
        int d  = t / 8 + i * 32;
        int ks = (t % 8) * 8;
        u16 tmp[8];
#pragma unroll
        for (int j = 0; j < 8; ++j) tmp[j] = tile[ks + j][d];
        *reinterpret_cast<u32x4*>(vtb + (size_t)d * SEQ + k0 + ks) =
            *reinterpret_cast<u32x4*>(tmp);
    }
}

template <bool USE_VT>
__global__ __launch_bounds__(256, 2) void attn_kernel(
    const float* __restrict__ qg, const float* __restrict__ kg,
    const void* __restrict__ vgv, const int* __restrict__ maskg,
    const float* __restrict__ ptg, float* __restrict__ outg) {
    __shared__ float qp[64][132];
    __shared__ int   mlds[4][16][68];
    __shared__ u16   plds[4][16][72];

    const int b    = blockIdx.y;
    const int q0   = blockIdx.x * 64;
    const int tid  = threadIdx.x;
    const int wave = tid >> 6;
    const int lane = tid & 63;
    const int quad = lane >> 4;
    const int c16  = lane & 15;

    const float* qb = qg + ((size_t)b * SEQ + q0) * DIM;
    const float* kb = kg + (size_t)b * SEQ * DIM;
    const int*   mb = maskg + ((size_t)b * SEQ + q0) * SEQ;

    const bf16x8 qA0 = cvt8(qb + (size_t)(wave * 16 + c16) * DIM + quad * 8);
    const bf16x8 qA1 = cvt8(qb + (size_t)(wave * 16 + c16) * DIM + 32 + quad * 8);

    for (int jt = 0; jt < 9; ++jt) {
        int j0 = jt * 16;
        int jr = min(j0 + c16, 128);
        bf16x8 b0 = cvt8(ptg + (size_t)jr * DIM + quad * 8);
        bf16x8 b1 = cvt8(ptg + (size_t)jr * DIM + 32 + quad * 8);
        f32x4 acc = {0.f, 0.f, 0.f, 0.f};
        acc = __builtin_amdgcn_mfma_f32_16x16x32_bf16(qA0, b0, acc, 0, 0, 0);
        acc = __builtin_amdgcn_mfma_f32_16x16x32_bf16(qA1, b1, acc, 0, 0, 0);
        int jcol = j0 + c16;
        if (jcol <= 128) {
#pragma unroll
            for (int r = 0; r < 4; ++r)
                qp[wave * 16 + quad * 4 + r][jcol] = acc[r];
        }
    }

    float m_run[4], l_run[4];
    f32x4 O[4];
#pragma unroll
    for (int r = 0; r < 4; ++r) { m_run[r] = -1e30f; l_run[r] = 0.f; }
#pragma unroll
    for (int d = 0; d < 4; ++d) O[d] = f32x4{0.f, 0.f, 0.f, 0.f};

#pragma unroll 1
    for (int kt = 0; kt < NKT; ++kt) {
        const int k0 = kt * 64;
        {
            int row_l = lane >> 2;
            const int* mrow = mb + (size_t)(wave * 16 + row_l) * SEQ + k0;
#pragma unroll
            for (int i = 0; i < 4; ++i) {
                int seg = (lane & 3) + i * 4;
                *reinterpret_cast<u32x4*>(&mlds[wave][row_l][seg * 4]) =
                    *reinterpret_cast<const u32x4*>(mrow + seg * 4);
            }
        }

        f32x4 S[4];
#pragma unroll
        for (int sub = 0; sub < 4; ++sub) {
            const float* kr = kb + (size_t)(k0 + sub * 16 + c16) * DIM;
            bf16x8 kb0 = cvt8(kr + quad * 8);
            bf16x8 kb1 = cvt8(kr + 32 + quad * 8);
            f32x4 acc = {0.f, 0.f, 0.f, 0.f};
            acc = __builtin_amdgcn_mfma_f32_16x16x32_bf16(qA0, kb0, acc, 0, 0, 0);
            acc = __builtin_amdgcn_mfma_f32_16x16x32_bf16(qA1, kb1, acc, 0, 0, 0);
            S[sub] = acc;
        }

        float sv[4][4];
#pragma unroll
        for (int sub = 0; sub < 4; ++sub) {
#pragma unroll
            for (int r = 0; r < 4; ++r) {
                int row_l = quad * 4 + r;
                int row_g = q0 + wave * 16 + row_l;
                int col_g = k0 + sub * 16 + c16;
                int rel = col_g - row_g;
                rel = rel < -64 ? -64 : (rel > 64 ? 64 : rel);
                float x = (S[sub][r] + qp[wave * 16 + row_l][rel + 64]) * 0.125f;
                int mv = mlds[wave][row_l][sub * 16 + c16];
                sv[sub][r] = mv ? -1e30f : x;
            }
        }

        float m_new[4], alpha[4];
#pragma unroll
        for (int r = 0; r < 4; ++r) {
            float rmax = fmaxf(fmaxf(sv[0][r], sv[1][r]), fmaxf(sv[2][r], sv[3][r]));
            rmax = fmaxf(rmax, __shfl_xor(rmax, 1));
            rmax = fmaxf(rmax, __shfl_xor(rmax, 2));
            rmax = fmaxf(rmax, __shfl_xor(rmax, 4));
            rmax = fmaxf(rmax, __shfl_xor(rmax, 8));
            m_new[r] = fmaxf(m_run[r], rmax);
            alpha[r] = __expf(m_run[r] - m_new[r]);
            m_run[r] = m_new[r];
        }
#pragma unroll
        for (int r = 0; r < 4; ++r) {
            float rs = 0.f;
#pragma unroll
            for (int sub = 0; sub < 4; ++sub) {
                float e = __expf(sv[sub][r] - m_new[r]);
                rs += e;
                plds[wave][quad * 4 + r][sub * 16 + c16] = f2bf(e);
            }
            rs += __shfl_xor(rs, 1);
            rs += __shfl_xor(rs, 2);
            rs += __shfl_xor(rs, 4);
            rs += __shfl_xor(rs, 8);
            l_run[r] = l_run[r] * alpha[r] + rs;
#pragma unroll
            for (int d = 0; d < 4; ++d) O[d][r] *= alpha[r];
        }

        bf16x8 pA0 = *reinterpret_cast<bf16x8*>(&plds[wave][c16][quad * 8]);
        bf16x8 pA1 = *reinterpret_cast<bf16x8*>(&plds[wave][c16][32 + quad * 8]);
#pragma unroll
        for (int d = 0; d < 4; ++d) {
            bf16x8 vb0, vb1;
            if (USE_VT) {
                const u16* vtb = (const u16*)vgv + (size_t)b * DIM * SEQ +
                                 (size_t)(d * 16 + c16) * SEQ + k0;
                vb0 = ldg8(vtb + quad * 8);
                vb1 = ldg8(vtb + 32 + quad * 8);
            } else {
                u16 t0[8], t1[8];
                const float* vbase = (const float*)vgv +
                                     ((size_t)b * SEQ + k0) * DIM + d * 16 + c16;
#pragma unroll
                for (int jj = 0; jj < 8; ++jj) {
                    t0[jj] = f2bf(vbase[(size_t)(quad * 8 + jj) * DIM]);
                    t1[jj] = f2bf(vbase[(size_t)(32 + quad * 8 + jj) * DIM]);
                }
                vb0 = __builtin_bit_cast(bf16x8, *reinterpret_cast<u32x4*>(t0));
                vb1 = __builtin_bit_cast(bf16x8, *reinterpret_cast<u32x4*>(t1));
            }
            O[d] = __builtin_amdgcn_mfma_f32_16x16x32_bf16(pA0, vb0, O[d], 0, 0, 0);
            O[d] = __builtin_amdgcn_mfma_f32_16x16x32_bf16(pA1, vb1, O[d], 0, 0, 0);
        }
    }

    float* ob = outg + ((size_t)b * SEQ + q0) * DIM;
#pragma unroll
    for (int r = 0; r < 4; ++r) {
        float inv = 1.f / l_run[r];
        int row_l = wave * 16 + quad * 4 + r;
#pragma unroll
        for (int d = 0; d < 4; ++d)
            ob[(size_t)row_l * DIM + d * 16 + c16] = O[d][r] * inv;
    }
}

// ---------------------------------------------------------------------------
extern "C" void kernel_launch(void* const* d_in, const int* in_sizes, int n_in,
                              void* d_out, int out_size, void* d_ws, size_t ws_size,
                              hipStream_t stream) {
    const float* q    = (const float*)d_in[0];
    const float* k    = (const float*)d_in[1];
    const float* v    = (const float*)d_in[2];
    const int*   mask = (const int*)d_in[3];
    const float* pt   = (const float*)d_in[4];
    float* out        = (float*)d_out;

    const size_t vt_bytes = (size_t)BATCH * SEQ * DIM * sizeof(u16);   // 4 MB
    const size_t kb_bytes = (size_t)BATCH * SEQ * DIM * sizeof(u16);   // 4 MB
    dim3 grid(SEQ / 64, BATCH);

    if (ws_size >= vt_bytes + kb_bytes) {
        u16* vt = (u16*)d_ws;
        u16* kb = (u16*)((char*)d_ws + vt_bytes);
        prep_kv<<<dim3(512), 256, 0, stream>>>(k, v, kb, vt);
        attn_fast8<<<grid, 512, 0, stream>>>(q, kb, vt, mask, pt, out);
    } else if (ws_size >= vt_bytes) {
        u16* vt = (u16*)d_ws;
        vt_kernel<<<grid, 256, 0, stream>>>(v, vt);
        attn_kernel<true><<<grid, 256, 0, stream>>>(q, k, (const void*)vt, mask, pt, out);
    } else {
        attn_kernel<false><<<grid, 256, 0, stream>>>(q, k, (const void*)v, mask, pt, out);
    }
}

// Round 9
// 258.308 us; speedup vs baseline: 1.3943x; 1.0380x over previous
//
#include <hip/hip_runtime.h>
#include <stdint.h>

#define BATCH 32
#define SEQ   1024
#define DIM   64
#define NKT   (SEQ / 64)

typedef uint8_t  u8;
typedef uint16_t u16;
typedef uint32_t u32;
typedef unsigned long long u64;
typedef __attribute__((ext_vector_type(8))) __bf16 bf16x8;
typedef __attribute__((ext_vector_type(4))) float  f32x4;
typedef __attribute__((ext_vector_type(4))) u32    u32x4;

__device__ __forceinline__ float fexp2(float x) {
#if __has_builtin(__builtin_amdgcn_exp2f)
    return __builtin_amdgcn_exp2f(x);
#else
    return exp2f(x);
#endif
}

__device__ __forceinline__ u16 f2bf(float f) {
    u32 x = __builtin_bit_cast(u32, f);
    x += 0x7FFFu + ((x >> 16) & 1u);   // round-to-nearest-even
    return (u16)(x >> 16);
}

__device__ __forceinline__ bf16x8 cvt8(const float* __restrict__ p) {
    f32x4 a = *reinterpret_cast<const f32x4*>(p);
    f32x4 b = *reinterpret_cast<const f32x4*>(p + 4);
    u16 t[8];
    t[0] = f2bf(a[0]); t[1] = f2bf(a[1]); t[2] = f2bf(a[2]); t[3] = f2bf(a[3]);
    t[4] = f2bf(b[0]); t[5] = f2bf(b[1]); t[6] = f2bf(b[2]); t[7] = f2bf(b[3]);
    return __builtin_bit_cast(bf16x8, *reinterpret_cast<u32x4*>(t));
}

__device__ __forceinline__ bf16x8 cvt8s(const float* __restrict__ p, float s) {
    f32x4 a = *reinterpret_cast<const f32x4*>(p);
    f32x4 b = *reinterpret_cast<const f32x4*>(p + 4);
    u16 t[8];
    t[0] = f2bf(a[0] * s); t[1] = f2bf(a[1] * s); t[2] = f2bf(a[2] * s); t[3] = f2bf(a[3] * s);
    t[4] = f2bf(b[0] * s); t[5] = f2bf(b[1] * s); t[6] = f2bf(b[2] * s); t[7] = f2bf(b[3] * s);
    return __builtin_bit_cast(bf16x8, *reinterpret_cast<u32x4*>(t));
}

__device__ __forceinline__ bf16x8 ldg8(const u16* p) {
    u32x4 u = *reinterpret_cast<const u32x4*>(p);
    return __builtin_bit_cast(bf16x8, u);
}

// pack 4 ints' nonzero-ness into 4 bytes of a u32
__device__ __forceinline__ u32 pack4(u32x4 a) {
    return (u32)(a[0] != 0) | ((u32)(a[1] != 0) << 8) |
           ((u32)(a[2] != 0) << 16) | ((u32)(a[3] != 0) << 24);
}

// ---------------------------------------------------------------------------
// prep_kv (512 blocks): K f32 -> bf16 row-major; V f32 -> Vt bf16 [B][D][S].
// ---------------------------------------------------------------------------
__global__ __launch_bounds__(256) void prep_kv(
    const float* __restrict__ kg, const float* __restrict__ vg,
    u16* __restrict__ kb, u16* __restrict__ vtb_) {
    __shared__ u16 tile[64][72];
    const int t  = threadIdx.x;
    const int b  = blockIdx.x >> 4;
    const int k0 = (blockIdx.x & 15) * 64;

    {   // K f32 -> bf16 row-major (64x64 tile)
        int kk = t >> 2;
        int d0 = (t & 3) * 16;
        const float* src = kg + ((size_t)b * SEQ + k0 + kk) * DIM + d0;
        u16 tmp[16];
#pragma unroll
        for (int i = 0; i < 4; ++i) {
            f32x4 a = *reinterpret_cast<const f32x4*>(src + i * 4);
            tmp[i * 4 + 0] = f2bf(a[0]); tmp[i * 4 + 1] = f2bf(a[1]);
            tmp[i * 4 + 2] = f2bf(a[2]); tmp[i * 4 + 3] = f2bf(a[3]);
        }
        u16* dst = kb + ((size_t)b * SEQ + k0 + kk) * DIM + d0;
        *reinterpret_cast<u32x4*>(dst)     = *reinterpret_cast<u32x4*>(tmp);
        *reinterpret_cast<u32x4*>(dst + 8) = *reinterpret_cast<u32x4*>(tmp + 8);
    }
    {   // V tile -> LDS bf16 -> transposed store
        const float* vb = vg + (size_t)b * SEQ * DIM;
        int kk = t >> 2;
        int d0 = (t & 3) * 16;
        const float* src = vb + (size_t)(k0 + kk) * DIM + d0;
        u16 tmp[16];
#pragma unroll
        for (int i = 0; i < 4; ++i) {
            f32x4 a = *reinterpret_cast<const f32x4*>(src + i * 4);
            tmp[i * 4 + 0] = f2bf(a[0]); tmp[i * 4 + 1] = f2bf(a[1]);
            tmp[i * 4 + 2] = f2bf(a[2]); tmp[i * 4 + 3] = f2bf(a[3]);
        }
        *reinterpret_cast<u32x4*>(&tile[kk][d0])     = *reinterpret_cast<u32x4*>(tmp);
        *reinterpret_cast<u32x4*>(&tile[kk][d0 + 8]) = *reinterpret_cast<u32x4*>(tmp + 8);
    }
    __syncthreads();
    u16* vtb = vtb_ + (size_t)b * DIM * SEQ;
#pragma unroll
    for (int i = 0; i < 2; ++i) {
        int d  = t / 8 + i * 32;
        int ks = (t % 8) * 8;
        u16 tmp[8];
#pragma unroll
        for (int j = 0; j < 8; ++j) tmp[j] = tile[ks + j][d];
        *reinterpret_cast<u32x4*>(vtb + (size_t)d * SEQ + k0 + ks) =
            *reinterpret_cast<u32x4*>(tmp);
    }
}

// ---------------------------------------------------------------------------
// attn_fast9: r8 (no-max softmax, direct int-mask) + r4's register pipeline:
//  - mask: 2-tile-deep prefetch (mreg[2][4], fully-unrolled loop -> static idx)
//  - K: next-tile register prefetch (consumed then refilled each iter)
//  - V: current-tile loads issued early (before exp work)
//  - far-tile shortcut: 5+ of 8 tiles skip the qp gather; e = exp2(S + c_row)
// __launch_bounds__(512,2): 256-VGPR cap (r3 lesson), occupancy-insensitive.
// ---------------------------------------------------------------------------
__global__ __launch_bounds__(512, 2) void attn_fast9(
    const float* __restrict__ qg, const u16* __restrict__ kbf,
    const u16* __restrict__ vt, const int* __restrict__ maskg,
    const float* __restrict__ ptg, float* __restrict__ outg) {
    __shared__ float qp[64][132];        // 33792 B; reused as combine buffer
    __shared__ u16   plds[8][16][72];    // 18432 B, per-wave P tile
    __shared__ u8    mlds[8][16][64];    //  8192 B, per-wave mask byte tile

    const int b    = blockIdx.y;
    const int q0   = blockIdx.x * 64;
    const int tid  = threadIdx.x;
    const int wave = tid >> 6;
    const int lane = tid & 63;
    const int wq   = wave & 3;
    const int wk   = wave >> 2;
    const int quad = lane >> 4;
    const int c16  = lane & 15;

    const float SC = 0.125f * 1.44269504088896340736f;  // 1/8 * log2(e)

    const float* qb = qg + ((size_t)b * SEQ + q0) * DIM;

    // Q A-fragments, pre-scaled (exp2 space)
    const bf16x8 qA0 = cvt8s(qb + (size_t)(wq * 16 + c16) * DIM + quad * 8, SC);
    const bf16x8 qA1 = cvt8s(qb + (size_t)(wq * 16 + c16) * DIM + 32 + quad * 8, SC);

    // qp[64][129] = (SC*Q)(64x64) . pos_table^T ; jt tiles split across wk
    {
        const int jt0 = wk ? 5 : 0, jt1 = wk ? 9 : 5;
        for (int jt = jt0; jt < jt1; ++jt) {
            int j0 = jt * 16;
            int jr = min(j0 + c16, 128);
            bf16x8 b0 = cvt8(ptg + (size_t)jr * DIM + quad * 8);
            bf16x8 b1 = cvt8(ptg + (size_t)jr * DIM + 32 + quad * 8);
            f32x4 acc = {0.f, 0.f, 0.f, 0.f};
            acc = __builtin_amdgcn_mfma_f32_16x16x32_bf16(qA0, b0, acc, 0, 0, 0);
            acc = __builtin_amdgcn_mfma_f32_16x16x32_bf16(qA1, b1, acc, 0, 0, 0);
            int jcol = j0 + c16;
            if (jcol <= 128) {
#pragma unroll
                for (int r = 0; r < 4; ++r)
                    qp[wq * 16 + quad * 4 + r][jcol] = acc[r];
            }
        }
    }
    __syncthreads();   // qp complete (both halves)

    // per-row saturation constants (one broadcast LDS read each)
    float cL[4], cR[4];
#pragma unroll
    for (int r = 0; r < 4; ++r) {
        cL[r] = qp[wq * 16 + quad * 4 + r][0];
        cR[r] = qp[wq * 16 + quad * 4 + r][128];
    }

    const u16* kb_base  = kbf + (size_t)b * SEQ * DIM;
    const u16* vtb_base = vt  + (size_t)b * DIM * SEQ;
    const int  row_min  = q0 + wq * 16;
    const int  ktbase   = wk * 8;

    // int-mask source for this lane: row q0+wq*16+(lane>>2), 16-int chunk (lane&3)
    const int* mrow = maskg + ((size_t)b * SEQ + q0 + wq * 16 + (lane >> 2)) * SEQ +
                      (lane & 3) * 16;

    // 2-deep mask prefetch: mreg[0] = tile ktbase, mreg[1] = tile ktbase+1
    u32x4 mreg[2][4];
#pragma unroll
    for (int s = 0; s < 2; ++s) {
        const int* p = mrow + (size_t)(ktbase + s) * 64;
        mreg[s][0] = *reinterpret_cast<const u32x4*>(p);
        mreg[s][1] = *reinterpret_cast<const u32x4*>(p + 4);
        mreg[s][2] = *reinterpret_cast<const u32x4*>(p + 8);
        mreg[s][3] = *reinterpret_cast<const u32x4*>(p + 12);
    }

    // K fragments for first tile, prefetched into registers
    bf16x8 kc0[4], kc1[4];
#pragma unroll
    for (int sub = 0; sub < 4; ++sub) {
        const u16* kr = kb_base + (size_t)(ktbase * 64 + sub * 16 + c16) * DIM;
        kc0[sub] = ldg8(kr + quad * 8);
        kc1[sub] = ldg8(kr + 32 + quad * 8);
    }

    float l_part[4];
    f32x4 O[4];
#pragma unroll
    for (int r = 0; r < 4; ++r) l_part[r] = 0.f;
#pragma unroll
    for (int d = 0; d < 4; ++d) O[d] = f32x4{0.f, 0.f, 0.f, 0.f};

#pragma unroll
    for (int j = 0; j < 8; ++j) {
        const int kt = ktbase + j;
        const int k0 = kt * 64;
        const int ms = j & 1;          // static after full unroll

        // stage this tile's mask bytes (per-wave LDS, in-order, no barrier)
        {
            u32x4 pk;
            pk[0] = pack4(mreg[ms][0]); pk[1] = pack4(mreg[ms][1]);
            pk[2] = pack4(mreg[ms][2]); pk[3] = pack4(mreg[ms][3]);
            *reinterpret_cast<u32x4*>(&mlds[wave][lane >> 2][(lane & 3) * 16]) = pk;
        }
        // refill this set with tile kt+2 (wrapped in-bounds; tail values unused)
        {
            const int* p = mrow + (size_t)((kt + 2) & 15) * 64;
            mreg[ms][0] = *reinterpret_cast<const u32x4*>(p);
            mreg[ms][1] = *reinterpret_cast<const u32x4*>(p + 4);
            mreg[ms][2] = *reinterpret_cast<const u32x4*>(p + 8);
            mreg[ms][3] = *reinterpret_cast<const u32x4*>(p + 12);
        }

        // --- S = (SC*Q) . K^T from prefetched registers --------------------
        f32x4 S[4];
        __builtin_amdgcn_s_setprio(1);
#pragma unroll
        for (int sub = 0; sub < 4; ++sub) {
            f32x4 acc = {0.f, 0.f, 0.f, 0.f};
            acc = __builtin_amdgcn_mfma_f32_16x16x32_bf16(qA0, kc0[sub], acc, 0, 0, 0);
            acc = __builtin_amdgcn_mfma_f32_16x16x32_bf16(qA1, kc1[sub], acc, 0, 0, 0);
            S[sub] = acc;
        }
        __builtin_amdgcn_s_setprio(0);

        // --- refill K registers with next tile (wrapped; hidden under exp) -
        {
            const int kn = (ktbase + ((j + 1) & 7)) * 64;
#pragma unroll
            for (int sub = 0; sub < 4; ++sub) {
                const u16* kr = kb_base + (size_t)(kn + sub * 16 + c16) * DIM;
                kc0[sub] = ldg8(kr + quad * 8);
                kc1[sub] = ldg8(kr + 32 + quad * 8);
            }
        }

        // --- issue current V loads early (consumed after exp work) ---------
        bf16x8 vf0[4], vf1[4];
#pragma unroll
        for (int d = 0; d < 4; ++d) {
            const u16* vr = vtb_base + (size_t)(d * 16 + c16) * SEQ + k0;
            vf0[d] = ldg8(vr + quad * 8);
            vf1[d] = ldg8(vr + 32 + quad * 8);
        }

        // --- logits -> e = exp2(.) raw; lane-local l; P to LDS -------------
        const bool farL = (k0 + 127 <= row_min);
        const bool farR = (k0 >= row_min + 79);

        if (farL | farR) {
#pragma unroll
            for (int r = 0; r < 4; ++r) {
                const int row_l = quad * 4 + r;
                const float c = farL ? cL[r] : cR[r];
                float rs = 0.f;
#pragma unroll
                for (int sub = 0; sub < 4; ++sub) {
                    u8 mv = mlds[wave][row_l][sub * 16 + c16];
                    float e = mv ? 0.f : fexp2(S[sub][r] + c);
                    rs += e;
                    plds[wave][row_l][sub * 16 + c16] = f2bf(e);
                }
                l_part[r] += rs;
            }
        } else {
#pragma unroll
            for (int r = 0; r < 4; ++r) {
                const int row_l = quad * 4 + r;
                const int row_g = row_min + row_l;
                float rs = 0.f;
#pragma unroll
                for (int sub = 0; sub < 4; ++sub) {
                    int col_g = k0 + sub * 16 + c16;
                    int rel = col_g - row_g;
                    rel = rel < -64 ? -64 : (rel > 64 ? 64 : rel);
                    float x = S[sub][r] + qp[wq * 16 + row_l][rel + 64];
                    u8 mv = mlds[wave][row_l][sub * 16 + c16];
                    float e = mv ? 0.f : fexp2(x);
                    rs += e;
                    plds[wave][row_l][sub * 16 + c16] = f2bf(e);
                }
                l_part[r] += rs;
            }
        }

        // --- P (A-layout from per-wave LDS) and PV accumulate --------------
        bf16x8 pA0 = *reinterpret_cast<bf16x8*>(&plds[wave][c16][quad * 8]);
        bf16x8 pA1 = *reinterpret_cast<bf16x8*>(&plds[wave][c16][32 + quad * 8]);
        __builtin_amdgcn_s_setprio(1);
#pragma unroll
        for (int d = 0; d < 4; ++d) {
            O[d] = __builtin_amdgcn_mfma_f32_16x16x32_bf16(pA0, vf0[d], O[d], 0, 0, 0);
            O[d] = __builtin_amdgcn_mfma_f32_16x16x32_bf16(pA1, vf1[d], O[d], 0, 0, 0);
        }
        __builtin_amdgcn_s_setprio(0);
    }

    // --- one l reduce at the end -------------------------------------------
    float l_run[4];
#pragma unroll
    for (int r = 0; r < 4; ++r) {
        float rs = l_part[r];
        rs += __shfl_xor(rs, 1);
        rs += __shfl_xor(rs, 2);
        rs += __shfl_xor(rs, 4);
        rs += __shfl_xor(rs, 8);
        l_run[r] = rs;
    }

    // --- merge the two K-halves: plain adds (same zero shift both) ---------
    __syncthreads();   // everyone done reading qp
    float* cmb = &qp[0][0];
    const int cbase = (wq * 64 + lane) * 24;
    if (wk == 1) {
#pragma unroll
        for (int r = 0; r < 4; ++r) cmb[cbase + r] = l_run[r];
#pragma unroll
        for (int d = 0; d < 4; ++d)
#pragma unroll
            for (int r = 0; r < 4; ++r)
                cmb[cbase + 4 + d * 4 + r] = O[d][r];
    }
    __syncthreads();
    if (wk == 0) {
        float* ob = outg + ((size_t)b * SEQ + q0) * DIM;
#pragma unroll
        for (int r = 0; r < 4; ++r) {
            float inv = 1.f / (l_run[r] + cmb[cbase + r]);
            int row_l = wq * 16 + quad * 4 + r;
#pragma unroll
            for (int d = 0; d < 4; ++d) {
                float o = O[d][r] + cmb[cbase + 4 + d * 4 + r];
                ob[(size_t)row_l * DIM + d * 16 + c16] = o * inv;
            }
        }
    }
}

// ---------------------------------------------------------------------------
// Fallback kernels (workspace too small for fast path).
// ---------------------------------------------------------------------------
__global__ __launch_bounds__(256) void vt_kernel(const float* __restrict__ v,
                                                 u16* __restrict__ vt) {
    __shared__ u16 tile[64][72];
    const int b  = blockIdx.y;
    const int k0 = blockIdx.x * 64;
    const int t  = threadIdx.x;
    const float* vb  = v  + (size_t)b * SEQ * DIM;
    u16*         vtb = vt + (size_t)b * DIM * SEQ;

    {
        int kk = t >> 2;
        int d0 = (t & 3) * 16;
        const float* src = vb + (size_t)(k0 + kk) * DIM + d0;
        u16 tmp[16];
#pragma unroll
        for (int i = 0; i < 4; ++i) {
            f32x4 a = *reinterpret_cast<const f32x4*>(src + i * 4);
            tmp[i * 4 + 0] = f2bf(a[0]); tmp[i * 4 + 1] = f2bf(a[1]);
            tmp[i * 4 + 2] = f2bf(a[2]); tmp[i * 4 + 3] = f2bf(a[3]);
        }
        *reinterpret_cast<u32x4*>(&tile[kk][d0])     = *reinterpret_cast<u32x4*>(tmp);
        *reinterpret_cast<u32x4*>(&tile[kk][d0 + 8]) = *reinterpret_cast<u32x4*>(tmp + 8);
    }
    __syncthreads();
#pragma unroll
    for (int i = 0; i < 2; ++i) {
        int d  = t / 8 + i * 32;
        int ks = (t % 8) * 8;
        u16 tmp[8];
#pragma unroll
        for (int j = 0; j < 8; ++j) tmp[j] = tile[ks + j][d];
        *reinterpret_cast<u32x4*>(vtb + (size_t)d * SEQ + k0 + ks) =
            *reinterpret_cast<u32x4*>(tmp);
    }
}

template <bool USE_VT>
__global__ __launch_bounds__(256, 2) void attn_kernel(
    const float* __restrict__ qg, const float* __restrict__ kg,
    const void* __restrict__ vgv, const int* __restrict__ maskg,
    const float* __restrict__ ptg, float* __restrict__ outg) {
    __shared__ float qp[64][132];
    __shared__ int   mlds[4][16][68];
    __shared__ u16   plds[4][16][72];

    const int b    = blockIdx.y;
    const int q0   = blockIdx.x * 64;
    const int tid  = threadIdx.x;
    const int wave = tid >> 6;
    const int lane = tid & 63;
    const int quad = lane >> 4;
    const int c16  = lane & 15;

    const float* qb = qg + ((size_t)b * SEQ + q0) * DIM;
    const float* kb = kg + (size_t)b * SEQ * DIM;
    const int*   mb = maskg + ((size_t)b * SEQ + q0) * SEQ;

    const bf16x8 qA0 = cvt8(qb + (size_t)(wave * 16 + c16) * DIM + quad * 8);
    const bf16x8 qA1 = cvt8(qb + (size_t)(wave * 16 + c16) * DIM + 32 + quad * 8);

    for (int jt = 0; jt < 9; ++jt) {
        int j0 = jt * 16;
        int jr = min(j0 + c16, 128);
        bf16x8 b0 = cvt8(ptg + (size_t)jr * DIM + quad * 8);
        bf16x8 b1 = cvt8(ptg + (size_t)jr * DIM + 32 + quad * 8);
        f32x4 acc = {0.f, 0.f, 0.f, 0.f};
        acc = __builtin_amdgcn_mfma_f32_16x16x32_bf16(qA0, b0, acc, 0, 0, 0);
        acc = __builtin_amdgcn_mfma_f32_16x16x32_bf16(qA1, b1, acc, 0, 0, 0);
        int jcol = j0 + c16;
        if (jcol <= 128) {
#pragma unroll
            for (int r = 0; r < 4; ++r)
                qp[wave * 16 + quad * 4 + r][jcol] = acc[r];
        }
    }

    float m_run[4], l_run[4];
    f32x4 O[4];
#pragma unroll
    for (int r = 0; r < 4; ++r) { m_run[r] = -1e30f; l_run[r] = 0.f; }
#pragma unroll
    for (int d = 0; d < 4; ++d) O[d] = f32x4{0.f, 0.f, 0.f, 0.f};

#pragma unroll 1
    for (int kt = 0; kt < NKT; ++kt) {
        const int k0 = kt * 64;
        {
            int row_l = lane >> 2;
            const int* mrow = mb + (size_t)(wave * 16 + row_l) * SEQ + k0;
#pragma unroll
            for (int i = 0; i < 4; ++i) {
                int seg = (lane & 3) + i * 4;
                *reinterpret_cast<u32x4*>(&mlds[wave][row_l][seg * 4]) =
                    *reinterpret_cast<const u32x4*>(mrow + seg * 4);
            }
        }

        f32x4 S[4];
#pragma unroll
        for (int sub = 0; sub < 4; ++sub) {
            const float* kr = kb + (size_t)(k0 + sub * 16 + c16) * DIM;
            bf16x8 kb0 = cvt8(kr + quad * 8);
            bf16x8 kb1 = cvt8(kr + 32 + quad * 8);
            f32x4 acc = {0.f, 0.f, 0.f, 0.f};
            acc = __builtin_amdgcn_mfma_f32_16x16x32_bf16(qA0, kb0, acc, 0, 0, 0);
            acc = __builtin_amdgcn_mfma_f32_16x16x32_bf16(qA1, kb1, acc, 0, 0, 0);
            S[sub] = acc;
        }

        float sv[4][4];
#pragma unroll
        for (int sub = 0; sub < 4; ++sub) {
#pragma unroll
            for (int r = 0; r < 4; ++r) {
                int row_l = quad * 4 + r;
                int row_g = q0 + wave * 16 + row_l;
                int col_g = k0 + sub * 16 + c16;
                int rel = col_g - row_g;
                rel = rel < -64 ? -64 : (rel > 64 ? 64 : rel);
                float x = (S[sub][r] + qp[wave * 16 + row_l][rel + 64]) * 0.125f;
                int mv = mlds[wave][row_l][sub * 16 + c16];
                sv[sub][r] = mv ? -1e30f : x;
            }
        }

        float m_new[4], alpha[4];
#pragma unroll
        for (int r = 0; r < 4; ++r) {
            float rmax = fmaxf(fmaxf(sv[0][r], sv[1][r]), fmaxf(sv[2][r], sv[3][r]));
            rmax = fmaxf(rmax, __shfl_xor(rmax, 1));
            rmax = fmaxf(rmax, __shfl_xor(rmax, 2));
            rmax = fmaxf(rmax, __shfl_xor(rmax, 4));
            rmax = fmaxf(rmax, __shfl_xor(rmax, 8));
            m_new[r] = fmaxf(m_run[r], rmax);
            alpha[r] = __expf(m_run[r] - m_new[r]);
            m_run[r] = m_new[r];
        }
#pragma unroll
        for (int r = 0; r < 4; ++r) {
            float rs = 0.f;
#pragma unroll
            for (int sub = 0; sub < 4; ++sub) {
                float e = __expf(sv[sub][r] - m_new[r]);
                rs += e;
                plds[wave][quad * 4 + r][sub * 16 + c16] = f2bf(e);
            }
            rs += __shfl_xor(rs, 1);
            rs += __shfl_xor(rs, 2);
            rs += __shfl_xor(rs, 4);
            rs += __shfl_xor(rs, 8);
            l_run[r] = l_run[r] * alpha[r] + rs;
#pragma unroll
            for (int d = 0; d < 4; ++d) O[d][r] *= alpha[r];
        }

        bf16x8 pA0 = *reinterpret_cast<bf16x8*>(&plds[wave][c16][quad * 8]);
        bf16x8 pA1 = *reinterpret_cast<bf16x8*>(&plds[wave][c16][32 + quad * 8]);
#pragma unroll
        for (int d = 0; d < 4; ++d) {
            bf16x8 vb0, vb1;
            if (USE_VT) {
                const u16* vtb = (const u16*)vgv + (size_t)b * DIM * SEQ +
                                 (size_t)(d * 16 + c16) * SEQ + k0;
                vb0 = ldg8(vtb + quad * 8);
                vb1 = ldg8(vtb + 32 + quad * 8);
            } else {
                u16 t0[8], t1[8];
                const float* vbase = (const float*)vgv +
                                     ((size_t)b * SEQ + k0) * DIM + d * 16 + c16;
#pragma unroll
                for (int jj = 0; jj < 8; ++jj) {
                    t0[jj] = f2bf(vbase[(size_t)(quad * 8 + jj) * DIM]);
                    t1[jj] = f2bf(vbase[(size_t)(32 + quad * 8 + jj) * DIM]);
                }
                vb0 = __builtin_bit_cast(bf16x8, *reinterpret_cast<u32x4*>(t0));
                vb1 = __builtin_bit_cast(bf16x8, *reinterpret_cast<u32x4*>(t1));
            }
            O[d] = __builtin_amdgcn_mfma_f32_16x16x32_bf16(pA0, vb0, O[d], 0, 0, 0);
            O[d] = __builtin_amdgcn_mfma_f32_16x16x32_bf16(pA1, vb1, O[d], 0, 0, 0);
        }
    }

    float* ob = outg + ((size_t)b * SEQ + q0) * DIM;
#pragma unroll
    for (int r = 0; r < 4; ++r) {
        float inv = 1.f / l_run[r];
        int row_l = wave * 16 + quad * 4 + r;
#pragma unroll
        for (int d = 0; d < 4; ++d)
            ob[(size_t)row_l * DIM + d * 16 + c16] = O[d][r] * inv;
    }
}

// ---------------------------------------------------------------------------
extern "C" void kernel_launch(void* const* d_in, const int* in_sizes, int n_in,
                              void* d_out, int out_size, void* d_ws, size_t ws_size,
                              hipStream_t stream) {
    const float* q    = (const float*)d_in[0];
    const float* k    = (const float*)d_in[1];
    const float* v    = (const float*)d_in[2];
    const int*   mask = (const int*)d_in[3];
    const float* pt   = (const float*)d_in[4];
    float* out        = (float*)d_out;

    const size_t vt_bytes = (size_t)BATCH * SEQ * DIM * sizeof(u16);   // 4 MB
    const size_t kb_bytes = (size_t)BATCH * SEQ * DIM * sizeof(u16);   // 4 MB
    dim3 grid(SEQ / 64, BATCH);

    if (ws_size >= vt_bytes + kb_bytes) {
        u16* vt = (u16*)d_ws;
        u16* kb = (u16*)((char*)d_ws + vt_bytes);
        prep_kv<<<dim3(512), 256, 0, stream>>>(k, v, kb, vt);
        attn_fast9<<<grid, 512, 0, stream>>>(q, kb, vt, mask, pt, out);
    } else if (ws_size >= vt_bytes) {
        u16* vt = (u16*)d_ws;
        vt_kernel<<<grid, 256, 0, stream>>>(v, vt);
        attn_kernel<true><<<grid, 256, 0, stream>>>(q, k, (const void*)vt, mask, pt, out);
    } else {
        attn_kernel<false><<<grid, 256, 0, stream>>>(q, k, (const void*)v, mask, pt, out);
    }
}